// Round 1
// baseline (11845.622 us; speedup 1.0000x reference)
//
#include <hip/hip_runtime.h>
#include <math.h>

#define N_NODES 50000
#define N_EDGES 1600000
#define NGRAPH  512
#define HID     128
#define EDIM    64
#define NCONV   4

// ---------------- embed: h = x @ W_emb + b_emb ----------------
__global__ __launch_bounds__(256) void k_embed(const float* __restrict__ x,
                                               const float* __restrict__ Wemb,
                                               const float* __restrict__ bemb,
                                               float* __restrict__ h) {
  int i = blockIdx.x * blockDim.x + threadIdx.x;
  if (i >= N_NODES * HID) return;
  int n = i >> 7, c = i & 127;
  const float* xr = x + (size_t)n * 9;
  float acc = bemb[c];
#pragma unroll
  for (int k = 0; k < 9; k++) acc = fmaf(xr[k], Wemb[k * HID + c], acc);
  h[i] = acc;
}

// ---------------- CSR build ----------------
__global__ __launch_bounds__(256) void k_count(const int* __restrict__ ei, int* __restrict__ cnt) {
  int e = blockIdx.x * blockDim.x + threadIdx.x;
  if (e >= N_EDGES) return;
  atomicAdd(&cnt[ei[N_EDGES + e]], 1);
}

__global__ __launch_bounds__(256) void k_scan1(const int* __restrict__ cnt, int* __restrict__ bsum) {
  __shared__ int s[256];
  int i = blockIdx.x * 256 + threadIdx.x;
  s[threadIdx.x] = (i < N_NODES) ? cnt[i] : 0;
  __syncthreads();
  for (int o = 128; o > 0; o >>= 1) {
    if (threadIdx.x < o) s[threadIdx.x] += s[threadIdx.x + o];
    __syncthreads();
  }
  if (threadIdx.x == 0) bsum[blockIdx.x] = s[0];
}

__global__ void k_scan2(int* __restrict__ bsum, int nb) {
  if (threadIdx.x == 0 && blockIdx.x == 0) {
    int acc = 0;
    for (int i = 0; i < nb; i++) { int v = bsum[i]; bsum[i] = acc; acc += v; }
  }
}

__global__ __launch_bounds__(256) void k_scan3(const int* __restrict__ cnt, const int* __restrict__ bsum,
                                               int* __restrict__ row_start, float* __restrict__ inv) {
  __shared__ int s[256];
  int i = blockIdx.x * 256 + threadIdx.x;
  int v = (i < N_NODES) ? cnt[i] : 0;
  s[threadIdx.x] = v;
  __syncthreads();
  for (int o = 1; o < 256; o <<= 1) {
    int t = (threadIdx.x >= o) ? s[threadIdx.x - o] : 0;
    __syncthreads();
    s[threadIdx.x] += t;
    __syncthreads();
  }
  if (i < N_NODES) {
    row_start[i + 1] = s[threadIdx.x] + bsum[blockIdx.x];
    inv[i] = 1.0f / (float)max(v, 1);
    if (i == 0) row_start[0] = 0;
  }
}

__global__ __launch_bounds__(256) void k_fill(const int* __restrict__ ei, const int* __restrict__ row_start,
                                              int* __restrict__ cur, int* __restrict__ eids,
                                              int* __restrict__ esrc) {
  int e = blockIdx.x * blockDim.x + threadIdx.x;
  if (e >= N_EDGES) return;
  int s = ei[e], d = ei[N_EDGES + e];
  int pos = row_start[d] + atomicAdd(&cur[d], 1);
  eids[pos] = e;
  esrc[pos] = s;
}

// ---------------- node projections: P[n][512] = [Fdst|Fsrc|Gdst|Gsrc] ----------------
__global__ __launch_bounds__(256) void k_nodeproj(const float* __restrict__ h,
                                                  const float* __restrict__ Wf_l,
                                                  const float* __restrict__ Ws_l,
                                                  const float* __restrict__ bf_l,
                                                  const float* __restrict__ bs_l,
                                                  float* __restrict__ P) {
  __shared__ float hrow[HID];
  int half = blockIdx.x & 1;
  int cc = half * 256 + threadIdx.x;
  int q = cc >> 7, col = cc & 127;
  const float* W = ((q < 2) ? Wf_l : Ws_l) + (size_t)(q & 1) * HID * HID + col;
  float w[HID];
#pragma unroll
  for (int k = 0; k < HID; k++) w[k] = W[(size_t)k * HID];
  float bias = (q == 0) ? bf_l[col] : ((q == 2) ? bs_l[col] : 0.f);
  for (int node = (blockIdx.x >> 1); node < N_NODES; node += (gridDim.x >> 1)) {
    __syncthreads();
    if (threadIdx.x < HID) hrow[threadIdx.x] = h[(size_t)node * HID + threadIdx.x];
    __syncthreads();
    float acc = bias;
    const float4* h4 = (const float4*)hrow;
#pragma unroll
    for (int k4 = 0; k4 < HID / 4; k4++) {
      float4 hv = h4[k4];
      acc = fmaf(hv.x, w[4 * k4 + 0], acc);
      acc = fmaf(hv.y, w[4 * k4 + 1], acc);
      acc = fmaf(hv.z, w[4 * k4 + 2], acc);
      acc = fmaf(hv.w, w[4 * k4 + 3], acc);
    }
    P[(size_t)node * 512 + cc] = acc;
  }
}

// ---------------- fused edge projection + message + mean-aggregate ----------------
// one wave per (node, channel-half); lane owns f_c and g_c with weight columns in VGPRs
__global__ __launch_bounds__(256) void k_edge(const float* __restrict__ P,
                                              const float* __restrict__ eattr,
                                              const int* __restrict__ row_start,
                                              const float* __restrict__ inv,
                                              const int* __restrict__ eids,
                                              const int* __restrict__ esrc,
                                              const float* __restrict__ Wfe,
                                              const float* __restrict__ Wse,
                                              float* __restrict__ aggr) {
  int lane = threadIdx.x & 63;
  int wid = blockIdx.x * (blockDim.x >> 6) + (threadIdx.x >> 6);
  int nw = gridDim.x * (blockDim.x >> 6);
  int half = wid & 1;
  int c = half * 64 + lane;
  float wf[64], wg[64];
#pragma unroll
  for (int k = 0; k < 64; k++) { wf[k] = Wfe[k * HID + c]; wg[k] = Wse[k * HID + c]; }
  for (int node = (wid >> 1); node < N_NODES; node += (nw >> 1)) {
    int rs = row_start[node], re = row_start[node + 1];
    float fd = P[(size_t)node * 512 + c];
    float gd = P[(size_t)node * 512 + 256 + c];
    float acc = 0.f;
    for (int pos = rs; pos < re; ++pos) {
      int eid = eids[pos];
      int src = esrc[pos];
      const float4* er = (const float4*)(eattr + (size_t)eid * EDIM);
      float f = fd + P[(size_t)src * 512 + 128 + c];
      float g = gd + P[(size_t)src * 512 + 384 + c];
#pragma unroll
      for (int k4 = 0; k4 < 16; k4++) {
        float4 ev = er[k4];
        f = fmaf(ev.x, wf[4 * k4 + 0], f);  g = fmaf(ev.x, wg[4 * k4 + 0], g);
        f = fmaf(ev.y, wf[4 * k4 + 1], f);  g = fmaf(ev.y, wg[4 * k4 + 1], g);
        f = fmaf(ev.z, wf[4 * k4 + 2], f);  g = fmaf(ev.z, wg[4 * k4 + 2], g);
        f = fmaf(ev.w, wf[4 * k4 + 3], f);  g = fmaf(ev.w, wg[4 * k4 + 3], g);
      }
      float sg = 1.f / (1.f + __expf(-f));
      float sp = fmaxf(g, 0.f) + log1pf(__expf(-fabsf(g)));
      acc += sg * sp;
    }
    aggr[(size_t)node * HID + c] = acc * inv[node];
  }
}

// ---------------- BN stats: hconv = aggr + h (in place), per-channel sums ----------------
__global__ __launch_bounds__(256) void k_bn1(float* __restrict__ hconv, const float* __restrict__ h,
                                             float* __restrict__ stats) {
  __shared__ float sb[512];
  int c = threadIdx.x & 127;
  int rstream = blockIdx.x * (blockDim.x >> 7) + (threadIdx.x >> 7);
  int nstream = gridDim.x * (blockDim.x >> 7);
  float s1 = 0.f, s2 = 0.f;
  for (int n = rstream; n < N_NODES; n += nstream) {
    size_t idx = (size_t)n * HID + c;
    float v = hconv[idx] + h[idx];
    hconv[idx] = v;
    s1 += v;
    s2 += v * v;
  }
  sb[threadIdx.x] = s1;
  sb[256 + threadIdx.x] = s2;
  __syncthreads();
  if (threadIdx.x < 128) {
    atomicAdd(&stats[c], sb[threadIdx.x] + sb[threadIdx.x + 128]);
    atomicAdd(&stats[128 + c], sb[256 + threadIdx.x] + sb[256 + threadIdx.x + 128]);
  }
}

__global__ void k_bn2(const float* __restrict__ stats, const float* __restrict__ gamma,
                      const float* __restrict__ beta, float* __restrict__ ss) {
  int c = threadIdx.x;
  if (c < 128) {
    float mu = stats[c] * (1.f / N_NODES);
    float var = stats[128 + c] * (1.f / N_NODES) - mu * mu;
    float sc = gamma[c] * rsqrtf(var + 1e-5f);
    ss[c] = sc;
    ss[128 + c] = beta[c] - mu * sc;
  }
}

__global__ __launch_bounds__(256) void k_bn3(const float* __restrict__ hconv, float* __restrict__ h,
                                             const float* __restrict__ ss) {
  int i = blockIdx.x * blockDim.x + threadIdx.x;
  if (i >= N_NODES * HID) return;
  int c = i & 127;
  float v = hconv[i] * ss[c] + ss[128 + c];
  h[i] = fmaxf(v, 0.f) + h[i];
}

// ---------------- pooling (batch is sorted -> binary search, no atomics) ----------------
__global__ __launch_bounds__(128) void k_pool(const float* __restrict__ h, const int* __restrict__ batch,
                                              float* __restrict__ pooled) {
  int g = blockIdx.x;
  int c = threadIdx.x;
  int lo = 0, hi = N_NODES;
  while (lo < hi) { int m = (lo + hi) >> 1; if (batch[m] < g) lo = m + 1; else hi = m; }
  int s = lo;
  lo = 0; hi = N_NODES;
  while (lo < hi) { int m = (lo + hi) >> 1; if (batch[m] < g + 1) lo = m + 1; else hi = m; }
  int e = lo;
  float acc = 0.f;
  for (int n = s; n < e; n++) acc += h[(size_t)n * HID + c];
  pooled[(size_t)g * HID + c] = acc / (float)max(e - s, 1);
}

// ---------------- head: softplus(pooled@W1+b1)@W2+b2 ----------------
__global__ __launch_bounds__(64) void k_head(const float* __restrict__ pooled, const float* __restrict__ W1,
                                             const float* __restrict__ b1, const float* __restrict__ W2,
                                             const float* __restrict__ b2, float* __restrict__ out) {
  int g = blockIdx.x;
  int j = threadIdx.x;
  float acc = b1[j];
#pragma unroll 16
  for (int k = 0; k < 128; k++) acc = fmaf(pooled[(size_t)g * HID + k], W1[k * 64 + j], acc);
  float z = fmaxf(acc, 0.f) + log1pf(__expf(-fabsf(acc)));
  float v = z * W2[j];
  for (int o = 32; o > 0; o >>= 1) v += __shfl_down(v, o);
  if (j == 0) out[g] = v + b2[0];
}

extern "C" void kernel_launch(void* const* d_in, const int* in_sizes, int n_in,
                              void* d_out, int out_size, void* d_ws, size_t ws_size,
                              hipStream_t stream) {
  const float* x     = (const float*)d_in[0];
  const int*   ei    = (const int*)d_in[1];
  const float* eattr = (const float*)d_in[2];
  const int*   batch = (const int*)d_in[3];
  const float* Wemb  = (const float*)d_in[4];
  const float* bemb  = (const float*)d_in[5];
  const float* Wf    = (const float*)d_in[6];
  const float* bf    = (const float*)d_in[7];
  const float* Ws    = (const float*)d_in[8];
  const float* bs    = (const float*)d_in[9];
  const float* gamma = (const float*)d_in[10];
  const float* beta  = (const float*)d_in[11];
  const float* W1    = (const float*)d_in[12];
  const float* b1    = (const float*)d_in[13];
  const float* W2    = (const float*)d_in[14];
  const float* b2    = (const float*)d_in[15];
  float* out = (float*)d_out;

  char* ws = (char*)d_ws;
  size_t off = 0;
  auto alloc = [&](size_t bytes) -> char* {
    char* p = ws + off;
    off += (bytes + 255) & ~(size_t)255;
    return p;
  };
  float* h         = (float*)alloc((size_t)N_NODES * HID * 4);
  float* P         = (float*)alloc((size_t)N_NODES * 512 * 4);
  float* aggr      = (float*)alloc((size_t)N_NODES * HID * 4);
  int*   row_start = (int*)alloc((size_t)(N_NODES + 1) * 4);
  float* inv       = (float*)alloc((size_t)N_NODES * 4);
  int*   eids      = (int*)alloc((size_t)N_EDGES * 4);
  int*   esrc      = (int*)alloc((size_t)N_EDGES * 4);
  char*  zbase     = ws + off;   // ---- zeroed region start ----
  int*   cnt       = (int*)alloc((size_t)N_NODES * 4);
  int*   cur       = (int*)alloc((size_t)N_NODES * 4);
  float* stats     = (float*)alloc((size_t)NCONV * 256 * 4);
  size_t zbytes    = (size_t)((ws + off) - zbase);
  float* ss        = (float*)alloc(256 * 4);
  int*   bsum      = (int*)alloc(256 * 4);
  float* pooled    = (float*)alloc((size_t)NGRAPH * HID * 4);
  (void)ws_size; (void)in_sizes; (void)n_in; (void)out_size;

  hipMemsetAsync(zbase, 0, zbytes, stream);

  k_embed<<<(N_NODES * HID + 255) / 256, 256, 0, stream>>>(x, Wemb, bemb, h);

  k_count<<<(N_EDGES + 255) / 256, 256, 0, stream>>>(ei, cnt);
  int nb = (N_NODES + 255) / 256;  // 196
  k_scan1<<<nb, 256, 0, stream>>>(cnt, bsum);
  k_scan2<<<1, 1, 0, stream>>>(bsum, nb);
  k_scan3<<<nb, 256, 0, stream>>>(cnt, bsum, row_start, inv);
  k_fill<<<(N_EDGES + 255) / 256, 256, 0, stream>>>(ei, row_start, cur, eids, esrc);

  for (int l = 0; l < NCONV; l++) {
    const float* Wf_l = Wf + (size_t)l * 320 * HID;
    const float* Ws_l = Ws + (size_t)l * 320 * HID;
    k_nodeproj<<<2048, 256, 0, stream>>>(h, Wf_l, Ws_l, bf + l * HID, bs + l * HID, P);
    k_edge<<<2048, 256, 0, stream>>>(P, eattr, row_start, inv, eids, esrc,
                                     Wf_l + 256 * HID, Ws_l + 256 * HID, aggr);
    k_bn1<<<128, 256, 0, stream>>>(aggr, h, stats + l * 256);
    k_bn2<<<1, 128, 0, stream>>>(stats + l * 256, gamma + l * HID, beta + l * HID, ss);
    k_bn3<<<(N_NODES * HID + 255) / 256, 256, 0, stream>>>(aggr, h, ss);
  }

  k_pool<<<NGRAPH, HID, 0, stream>>>(h, batch, pooled);
  k_head<<<NGRAPH, 64, 0, stream>>>(pooled, W1, b1, W2, b2, out);
}

// Round 3
// 3670.106 us; speedup vs baseline: 3.2276x; 3.2276x over previous
//
#include <hip/hip_runtime.h>
#include <math.h>

#define N_NODES 50000
#define N_EDGES 1600000
#define NGRAPH  512
#define HID     128
#define EDIM    64
#define NCONV   4

typedef __attribute__((ext_vector_type(8))) short short8;
typedef __attribute__((ext_vector_type(4))) float f32x4;
typedef unsigned int  u32;
typedef unsigned short u16;

#define MFMA16(a, b, c) __builtin_amdgcn_mfma_f32_16x16x32_bf16(a, b, c, 0, 0, 0)

__device__ __forceinline__ float fsig(float x) {
  return __fdividef(1.f, 1.f + __expf(-x));
}
__device__ __forceinline__ float fsp(float x) {
  return fmaxf(x, 0.f) + __logf(1.f + __expf(-fabsf(x)));
}
__device__ __forceinline__ u32 f2bf_pack(float lo, float hi) {
  u32 a = __float_as_uint(lo), b = __float_as_uint(hi);
  u32 ra = (a + 0x7fff + ((a >> 16) & 1)) >> 16;
  u32 rb = (b + 0x7fff + ((b >> 16) & 1)) & 0xffff0000u;
  return ra | rb;
}
// pack 8 consecutive f32 (two float4) into 8 bf16 (RNE)
__device__ __forceinline__ short8 cvt8(float4 a, float4 b) {
  union { short8 s; u32 u[4]; } r;
  r.u[0] = f2bf_pack(a.x, a.y);
  r.u[1] = f2bf_pack(a.z, a.w);
  r.u[2] = f2bf_pack(b.x, b.y);
  r.u[3] = f2bf_pack(b.z, b.w);
  return r.s;
}

// ---------------- embed ----------------
__global__ __launch_bounds__(256) void k_embed(const float* __restrict__ x,
                                               const float* __restrict__ Wemb,
                                               const float* __restrict__ bemb,
                                               float* __restrict__ h) {
  int i = blockIdx.x * blockDim.x + threadIdx.x;
  if (i >= N_NODES * HID) return;
  int n = i >> 7, c = i & 127;
  const float* xr = x + (size_t)n * 9;
  float acc = bemb[c];
#pragma unroll
  for (int k = 0; k < 9; k++) acc = fmaf(xr[k], Wemb[k * HID + c], acc);
  h[i] = acc;
}

// ---------------- CSR build ----------------
__global__ __launch_bounds__(256) void k_count(const int* __restrict__ ei, int* __restrict__ cnt) {
  int e = blockIdx.x * blockDim.x + threadIdx.x;
  if (e >= N_EDGES) return;
  atomicAdd(&cnt[ei[N_EDGES + e]], 1);
}

__global__ __launch_bounds__(256) void k_scan1(const int* __restrict__ cnt, int* __restrict__ bsum) {
  __shared__ int s[256];
  int i = blockIdx.x * 256 + threadIdx.x;
  s[threadIdx.x] = (i < N_NODES) ? cnt[i] : 0;
  __syncthreads();
  for (int o = 128; o > 0; o >>= 1) {
    if (threadIdx.x < o) s[threadIdx.x] += s[threadIdx.x + o];
    __syncthreads();
  }
  if (threadIdx.x == 0) bsum[blockIdx.x] = s[0];
}

__global__ void k_scan2(int* __restrict__ bsum, int nb) {
  if (threadIdx.x == 0 && blockIdx.x == 0) {
    int acc = 0;
    for (int i = 0; i < nb; i++) { int v = bsum[i]; bsum[i] = acc; acc += v; }
  }
}

__global__ __launch_bounds__(256) void k_scan3(const int* __restrict__ cnt, const int* __restrict__ bsum,
                                               int* __restrict__ row_start, float* __restrict__ inv) {
  __shared__ int s[256];
  int i = blockIdx.x * 256 + threadIdx.x;
  int v = (i < N_NODES) ? cnt[i] : 0;
  s[threadIdx.x] = v;
  __syncthreads();
  for (int o = 1; o < 256; o <<= 1) {
    int t = (threadIdx.x >= o) ? s[threadIdx.x - o] : 0;
    __syncthreads();
    s[threadIdx.x] += t;
    __syncthreads();
  }
  if (i < N_NODES) {
    row_start[i + 1] = s[threadIdx.x] + bsum[blockIdx.x];
    inv[i] = 1.0f / (float)max(v, 1);
    if (i == 0) row_start[0] = 0;
  }
}

__global__ __launch_bounds__(256) void k_fill(const int* __restrict__ ei, const int* __restrict__ row_start,
                                              int* __restrict__ cur, int* __restrict__ eids,
                                              int* __restrict__ esrc) {
  int e = blockIdx.x * blockDim.x + threadIdx.x;
  if (e >= N_EDGES) return;
  int s = ei[e], d = ei[N_EDGES + e];
  int pos = row_start[d] + atomicAdd(&cur[d], 1);
  eids[pos] = e;
  esrc[pos] = s;
}

// ---------------- node projections: P[n][512] = [Fdst|Fsrc|Gdst|Gsrc] ----------------
__global__ __launch_bounds__(256) void k_nodeproj(const float* __restrict__ h,
                                                  const float* __restrict__ Wf_l,
                                                  const float* __restrict__ Ws_l,
                                                  const float* __restrict__ bf_l,
                                                  const float* __restrict__ bs_l,
                                                  float* __restrict__ P) {
  __shared__ float hrow[HID];
  int half = blockIdx.x & 1;
  int cc = half * 256 + threadIdx.x;
  int q = cc >> 7, col = cc & 127;
  const float* W = ((q < 2) ? Wf_l : Ws_l) + (size_t)(q & 1) * HID * HID + col;
  float w[HID];
#pragma unroll
  for (int k = 0; k < HID; k++) w[k] = W[(size_t)k * HID];
  float bias = (q == 0) ? bf_l[col] : ((q == 2) ? bs_l[col] : 0.f);
  for (int node = (blockIdx.x >> 1); node < N_NODES; node += (gridDim.x >> 1)) {
    __syncthreads();
    if (threadIdx.x < HID) hrow[threadIdx.x] = h[(size_t)node * HID + threadIdx.x];
    __syncthreads();
    float acc = bias;
    const float4* h4 = (const float4*)hrow;
#pragma unroll
    for (int k4 = 0; k4 < HID / 4; k4++) {
      float4 hv = h4[k4];
      acc = fmaf(hv.x, w[4 * k4 + 0], acc);
      acc = fmaf(hv.y, w[4 * k4 + 1], acc);
      acc = fmaf(hv.z, w[4 * k4 + 2], acc);
      acc = fmaf(hv.w, w[4 * k4 + 3], acc);
    }
    P[(size_t)node * 512 + cc] = acc;
  }
}

// ---------------- B-fragment prep: W_edge [64,128] -> MFMA frag order, hi+lo bf16 ----------------
// Bfrag[nt 0..15][kstep 0..1][lane 0..63][i 0..7]; nt<8 = f (Wf), nt>=8 = g (Ws)
// element = W[k = s*32 + (lane>>4)*8 + i][col = (nt&7)*16 + (lane&15)]
__global__ __launch_bounds__(256) void k_prepB(const float* __restrict__ Wf_l,
                                               const float* __restrict__ Ws_l,
                                               u16* __restrict__ Bhi, u16* __restrict__ Blo) {
  int tid = blockIdx.x * 256 + threadIdx.x;
  if (tid >= 16384) return;
  int i = tid & 7, lane = (tid >> 3) & 63, s = (tid >> 9) & 1, nt = tid >> 10;
  int k = s * 32 + ((lane >> 4) << 3) + i;
  int col = ((nt & 7) << 4) + (lane & 15);
  const float* W = ((nt < 8) ? Wf_l : Ws_l) + 256 * HID;  // edge-attr part of weight
  float wv = W[k * HID + col];
  u32 u = __float_as_uint(wv);
  u16 hb = (u16)((u + 0x7fff + ((u >> 16) & 1)) >> 16);
  float hf = __uint_as_float((u32)hb << 16);
  float lo = wv - hf;
  u32 ul = __float_as_uint(lo);
  u16 lb = (u16)((ul + 0x7fff + ((ul >> 16) & 1)) >> 16);
  Bhi[tid] = hb;
  Blo[tid] = lb;
}

// ---------------- fused edge MFMA + message + mean-aggregate ----------------
// block = 4 waves, all on the same node; wave w owns cols [32w,32w+32) of f AND g.
// M-tile = 16 edges (CSR rows of the node), K = 64 (edge_attr), 2 passes (W hi+lo).
__global__ __launch_bounds__(256) void k_edge_mfma(
    const float* __restrict__ P, const float* __restrict__ eattr,
    const int* __restrict__ row_start, const float* __restrict__ inv,
    const int* __restrict__ eids, const int* __restrict__ esrc,
    const u16* __restrict__ Bhi, const u16* __restrict__ Blo,
    float* __restrict__ aggr) {
  const int lane = threadIdx.x & 63;
  const int w = threadIdx.x >> 6;
  const int l15 = lane & 15, lg = lane >> 4;
  const int cb = w * 32;

  const short8* BH = (const short8*)Bhi;
  const short8* BL = (const short8*)Blo;
  short8 bh[4][2], bl[4][2];
  const int nts[4] = {2 * w, 2 * w + 1, 8 + 2 * w, 9 + 2 * w};
#pragma unroll
  for (int t = 0; t < 4; t++) {
#pragma unroll
    for (int s = 0; s < 2; s++) {
      bh[t][s] = BH[(nts[t] * 2 + s) * 64 + lane];
      bl[t][s] = BL[(nts[t] * 2 + s) * 64 + lane];
    }
  }

  for (int node = blockIdx.x; node < N_NODES; node += gridDim.x) {
    int rs = row_start[node], re = row_start[node + 1];
    int deg = re - rs;
    const float* Pn = P + (size_t)node * 512;
    float fd0 = Pn[cb + l15];
    float fd1 = Pn[cb + 16 + l15];
    float gd0 = Pn[256 + cb + l15];
    float gd1 = Pn[256 + cb + 16 + l15];
    float acc0 = 0.f, acc1 = 0.f;
    int ntile = (deg + 15) >> 4;
    for (int mt = 0; mt < ntile; mt++) {
      int base = rs + mt * 16;
      int pos = min(base + l15, re - 1);
      int eid = eids[pos];
      int srcl = esrc[pos];
      const float* ar = eattr + (size_t)eid * EDIM + (lg << 3);
      float4 a0 = *(const float4*)(ar);
      float4 a1 = *(const float4*)(ar + 4);
      float4 a2 = *(const float4*)(ar + 32);
      float4 a3 = *(const float4*)(ar + 36);
      short8 af0 = cvt8(a0, a1);   // kstep 0
      short8 af1 = cvt8(a2, a3);   // kstep 1
      f32x4 d0 = {0.f, 0.f, 0.f, 0.f}, d1 = d0, d2 = d0, d3 = d0;
      d0 = MFMA16(af0, bh[0][0], d0); d0 = MFMA16(af1, bh[0][1], d0);
      d0 = MFMA16(af0, bl[0][0], d0); d0 = MFMA16(af1, bl[0][1], d0);
      d1 = MFMA16(af0, bh[1][0], d1); d1 = MFMA16(af1, bh[1][1], d1);
      d1 = MFMA16(af0, bl[1][0], d1); d1 = MFMA16(af1, bl[1][1], d1);
      d2 = MFMA16(af0, bh[2][0], d2); d2 = MFMA16(af1, bh[2][1], d2);
      d2 = MFMA16(af0, bl[2][0], d2); d2 = MFMA16(af1, bl[2][1], d2);
      d3 = MFMA16(af0, bh[3][0], d3); d3 = MFMA16(af1, bh[3][1], d3);
      d3 = MFMA16(af0, bl[3][0], d3); d3 = MFMA16(af1, bl[3][1], d3);
      // src node id for each D row (rows lg*4+r live in lanes 0..15 by row)
      int s0 = __shfl(srcl, (lg << 2) + 0);
      int s1 = __shfl(srcl, (lg << 2) + 1);
      int s2 = __shfl(srcl, (lg << 2) + 2);
      int s3 = __shfl(srcl, (lg << 2) + 3);
      const int srcr[4] = {s0, s1, s2, s3};
      bool fullt = ((mt + 1) * 16 <= deg);
#pragma unroll
      for (int r = 0; r < 4; r++) {
        const float* Ps = P + (size_t)srcr[r] * 512;
        float f0 = d0[r] + fd0 + Ps[128 + cb + l15];
        float f1 = d1[r] + fd1 + Ps[128 + cb + 16 + l15];
        float g0 = d2[r] + gd0 + Ps[384 + cb + l15];
        float g1 = d3[r] + gd1 + Ps[384 + cb + 16 + l15];
        float m0 = fsig(f0) * fsp(g0);
        float m1 = fsig(f1) * fsp(g1);
        if (!fullt) {
          int row = mt * 16 + (lg << 2) + r;
          if (row >= deg) { m0 = 0.f; m1 = 0.f; }
        }
        acc0 += m0;
        acc1 += m1;
      }
    }
    acc0 += __shfl_xor(acc0, 16); acc0 += __shfl_xor(acc0, 32);
    acc1 += __shfl_xor(acc1, 16); acc1 += __shfl_xor(acc1, 32);
    float iv = inv[node];
    if (lane < 16)       aggr[(size_t)node * HID + cb + lane] = acc0 * iv;
    else if (lane < 32)  aggr[(size_t)node * HID + cb + 16 + l15] = acc1 * iv;
  }
}

// ---------------- BN ----------------
__global__ __launch_bounds__(256) void k_bn1(float* __restrict__ hconv, const float* __restrict__ h,
                                             float* __restrict__ stats) {
  __shared__ float sb[512];
  int c = threadIdx.x & 127;
  int rstream = blockIdx.x * (blockDim.x >> 7) + (threadIdx.x >> 7);
  int nstream = gridDim.x * (blockDim.x >> 7);
  float s1 = 0.f, s2 = 0.f;
  for (int n = rstream; n < N_NODES; n += nstream) {
    size_t idx = (size_t)n * HID + c;
    float v = hconv[idx] + h[idx];
    hconv[idx] = v;
    s1 += v;
    s2 += v * v;
  }
  sb[threadIdx.x] = s1;
  sb[256 + threadIdx.x] = s2;
  __syncthreads();
  if (threadIdx.x < 128) {
    atomicAdd(&stats[c], sb[threadIdx.x] + sb[threadIdx.x + 128]);
    atomicAdd(&stats[128 + c], sb[256 + threadIdx.x] + sb[256 + threadIdx.x + 128]);
  }
}

__global__ void k_bn2(const float* __restrict__ stats, const float* __restrict__ gamma,
                      const float* __restrict__ beta, float* __restrict__ ss) {
  int c = threadIdx.x;
  if (c < 128) {
    float mu = stats[c] * (1.f / N_NODES);
    float var = stats[128 + c] * (1.f / N_NODES) - mu * mu;
    float sc = gamma[c] * rsqrtf(var + 1e-5f);
    ss[c] = sc;
    ss[128 + c] = beta[c] - mu * sc;
  }
}

__global__ __launch_bounds__(256) void k_bn3(const float* __restrict__ hconv, float* __restrict__ h,
                                             const float* __restrict__ ss) {
  int i = blockIdx.x * blockDim.x + threadIdx.x;
  if (i >= N_NODES * HID) return;
  int c = i & 127;
  float v = hconv[i] * ss[c] + ss[128 + c];
  h[i] = fmaxf(v, 0.f) + h[i];
}

// ---------------- pooling ----------------
__global__ __launch_bounds__(128) void k_pool(const float* __restrict__ h, const int* __restrict__ batch,
                                              float* __restrict__ pooled) {
  int g = blockIdx.x;
  int c = threadIdx.x;
  int lo = 0, hi = N_NODES;
  while (lo < hi) { int m = (lo + hi) >> 1; if (batch[m] < g) lo = m + 1; else hi = m; }
  int s = lo;
  lo = 0; hi = N_NODES;
  while (lo < hi) { int m = (lo + hi) >> 1; if (batch[m] < g + 1) lo = m + 1; else hi = m; }
  int e = lo;
  float acc = 0.f;
  for (int n = s; n < e; n++) acc += h[(size_t)n * HID + c];
  pooled[(size_t)g * HID + c] = acc / (float)max(e - s, 1);
}

// ---------------- head ----------------
__global__ __launch_bounds__(64) void k_head(const float* __restrict__ pooled, const float* __restrict__ W1,
                                             const float* __restrict__ b1, const float* __restrict__ W2,
                                             const float* __restrict__ b2, float* __restrict__ out) {
  int g = blockIdx.x;
  int j = threadIdx.x;
  float acc = b1[j];
#pragma unroll 16
  for (int k = 0; k < 128; k++) acc = fmaf(pooled[(size_t)g * HID + k], W1[k * 64 + j], acc);
  float z = fmaxf(acc, 0.f) + __logf(1.f + __expf(-fabsf(acc)));
  float v = z * W2[j];
  for (int o = 32; o > 0; o >>= 1) v += __shfl_down(v, o);
  if (j == 0) out[g] = v + b2[0];
}

extern "C" void kernel_launch(void* const* d_in, const int* in_sizes, int n_in,
                              void* d_out, int out_size, void* d_ws, size_t ws_size,
                              hipStream_t stream) {
  const float* x     = (const float*)d_in[0];
  const int*   ei    = (const int*)d_in[1];
  const float* eattr = (const float*)d_in[2];
  const int*   batch = (const int*)d_in[3];
  const float* Wemb  = (const float*)d_in[4];
  const float* bemb  = (const float*)d_in[5];
  const float* Wf    = (const float*)d_in[6];
  const float* bf    = (const float*)d_in[7];
  const float* Ws    = (const float*)d_in[8];
  const float* bs    = (const float*)d_in[9];
  const float* gamma = (const float*)d_in[10];
  const float* beta  = (const float*)d_in[11];
  const float* W1    = (const float*)d_in[12];
  const float* b1    = (const float*)d_in[13];
  const float* W2    = (const float*)d_in[14];
  const float* b2    = (const float*)d_in[15];
  float* out = (float*)d_out;

  char* ws = (char*)d_ws;
  size_t off = 0;
  auto alloc = [&](size_t bytes) -> char* {
    char* p = ws + off;
    off += (bytes + 255) & ~(size_t)255;
    return p;
  };
  float* h         = (float*)alloc((size_t)N_NODES * HID * 4);
  float* P         = (float*)alloc((size_t)N_NODES * 512 * 4);
  float* aggr      = (float*)alloc((size_t)N_NODES * HID * 4);
  int*   row_start = (int*)alloc((size_t)(N_NODES + 1) * 4);
  float* inv       = (float*)alloc((size_t)N_NODES * 4);
  int*   eids      = (int*)alloc((size_t)N_EDGES * 4);
  int*   esrc      = (int*)alloc((size_t)N_EDGES * 4);
  u16*   Bhi       = (u16*)alloc((size_t)16384 * 2);
  u16*   Blo       = (u16*)alloc((size_t)16384 * 2);
  char*  zbase     = ws + off;   // ---- zeroed region start ----
  int*   cnt       = (int*)alloc((size_t)N_NODES * 4);
  int*   cur       = (int*)alloc((size_t)N_NODES * 4);
  float* stats     = (float*)alloc((size_t)NCONV * 256 * 4);
  size_t zbytes    = (size_t)((ws + off) - zbase);
  float* ss        = (float*)alloc(256 * 4);
  int*   bsum      = (int*)alloc(256 * 4);
  float* pooled    = (float*)alloc((size_t)NGRAPH * HID * 4);
  (void)ws_size; (void)in_sizes; (void)n_in; (void)out_size;

  hipMemsetAsync(zbase, 0, zbytes, stream);

  k_embed<<<(N_NODES * HID + 255) / 256, 256, 0, stream>>>(x, Wemb, bemb, h);

  k_count<<<(N_EDGES + 255) / 256, 256, 0, stream>>>(ei, cnt);
  int nb = (N_NODES + 255) / 256;  // 196
  k_scan1<<<nb, 256, 0, stream>>>(cnt, bsum);
  k_scan2<<<1, 1, 0, stream>>>(bsum, nb);
  k_scan3<<<nb, 256, 0, stream>>>(cnt, bsum, row_start, inv);
  k_fill<<<(N_EDGES + 255) / 256, 256, 0, stream>>>(ei, row_start, cur, eids, esrc);

  for (int l = 0; l < NCONV; l++) {
    const float* Wf_l = Wf + (size_t)l * 320 * HID;
    const float* Ws_l = Ws + (size_t)l * 320 * HID;
    k_nodeproj<<<2048, 256, 0, stream>>>(h, Wf_l, Ws_l, bf + l * HID, bs + l * HID, P);
    k_prepB<<<64, 256, 0, stream>>>(Wf_l, Ws_l, Bhi, Blo);
    k_edge_mfma<<<2048, 256, 0, stream>>>(P, eattr, row_start, inv, eids, esrc, Bhi, Blo, aggr);
    k_bn1<<<128, 256, 0, stream>>>(aggr, h, stats + l * 256);
    k_bn2<<<1, 128, 0, stream>>>(stats + l * 256, gamma + l * HID, beta + l * HID, ss);
    k_bn3<<<(N_NODES * HID + 255) / 256, 256, 0, stream>>>(aggr, h, ss);
  }

  k_pool<<<NGRAPH, HID, 0, stream>>>(h, batch, pooled);
  k_head<<<NGRAPH, 64, 0, stream>>>(pooled, W1, b1, W2, b2, out);
}

// Round 4
// 3639.193 us; speedup vs baseline: 3.2550x; 1.0085x over previous
//
#include <hip/hip_runtime.h>
#include <math.h>

#define N_NODES 50000
#define N_EDGES 1600000
#define NGRAPH  512
#define HID     128
#define EDIM    64
#define NCONV   4

typedef __attribute__((ext_vector_type(8))) short short8;
typedef __attribute__((ext_vector_type(4))) float f32x4;
typedef unsigned int  u32;
typedef unsigned short u16;

#define MFMA16(a, b, c) __builtin_amdgcn_mfma_f32_16x16x32_bf16(a, b, c, 0, 0, 0)

__device__ __forceinline__ float fsig(float x) {
  return __fdividef(1.f, 1.f + __expf(-x));
}
__device__ __forceinline__ float fsp(float x) {
  return fmaxf(x, 0.f) + __logf(1.f + __expf(-fabsf(x)));
}
__device__ __forceinline__ u32 f2bf_pack(float lo, float hi) {
  u32 a = __float_as_uint(lo), b = __float_as_uint(hi);
  u32 ra = (a + 0x7fff + ((a >> 16) & 1)) >> 16;
  u32 rb = (b + 0x7fff + ((b >> 16) & 1)) & 0xffff0000u;
  return ra | rb;
}

// ---------------- embed ----------------
__global__ __launch_bounds__(256) void k_embed(const float* __restrict__ x,
                                               const float* __restrict__ Wemb,
                                               const float* __restrict__ bemb,
                                               float* __restrict__ h) {
  int i = blockIdx.x * blockDim.x + threadIdx.x;
  if (i >= N_NODES * HID) return;
  int n = i >> 7, c = i & 127;
  const float* xr = x + (size_t)n * 9;
  float acc = bemb[c];
#pragma unroll
  for (int k = 0; k < 9; k++) acc = fmaf(xr[k], Wemb[k * HID + c], acc);
  h[i] = acc;
}

// ---------------- CSR build ----------------
__global__ __launch_bounds__(256) void k_count(const int* __restrict__ ei, int* __restrict__ cnt) {
  int e = blockIdx.x * blockDim.x + threadIdx.x;
  if (e >= N_EDGES) return;
  atomicAdd(&cnt[ei[N_EDGES + e]], 1);
}

__global__ __launch_bounds__(256) void k_scan1(const int* __restrict__ cnt, int* __restrict__ bsum) {
  __shared__ int s[256];
  int i = blockIdx.x * 256 + threadIdx.x;
  s[threadIdx.x] = (i < N_NODES) ? cnt[i] : 0;
  __syncthreads();
  for (int o = 128; o > 0; o >>= 1) {
    if (threadIdx.x < o) s[threadIdx.x] += s[threadIdx.x + o];
    __syncthreads();
  }
  if (threadIdx.x == 0) bsum[blockIdx.x] = s[0];
}

// parallel exclusive scan of nb (<=256) block sums, one 256-thread block
__global__ __launch_bounds__(256) void k_scan2(int* __restrict__ bsum, int nb) {
  __shared__ int s[256];
  int tid = threadIdx.x;
  s[tid] = (tid < nb) ? bsum[tid] : 0;
  __syncthreads();
  for (int o = 1; o < 256; o <<= 1) {
    int t = (tid >= o) ? s[tid - o] : 0;
    __syncthreads();
    s[tid] += t;
    __syncthreads();
  }
  if (tid < nb) bsum[tid] = (tid == 0) ? 0 : s[tid - 1];
}

__global__ __launch_bounds__(256) void k_scan3(const int* __restrict__ cnt, const int* __restrict__ bsum,
                                               int* __restrict__ row_start, float* __restrict__ inv) {
  __shared__ int s[256];
  int i = blockIdx.x * 256 + threadIdx.x;
  int v = (i < N_NODES) ? cnt[i] : 0;
  s[threadIdx.x] = v;
  __syncthreads();
  for (int o = 1; o < 256; o <<= 1) {
    int t = (threadIdx.x >= o) ? s[threadIdx.x - o] : 0;
    __syncthreads();
    s[threadIdx.x] += t;
    __syncthreads();
  }
  if (i < N_NODES) {
    row_start[i + 1] = s[threadIdx.x] + bsum[blockIdx.x];
    inv[i] = 1.0f / (float)max(v, 1);
    if (i == 0) row_start[0] = 0;
  }
}

__global__ __launch_bounds__(256) void k_fill(const int* __restrict__ ei, const int* __restrict__ row_start,
                                              int* __restrict__ cur, int* __restrict__ eids,
                                              int* __restrict__ esrc) {
  int e = blockIdx.x * blockDim.x + threadIdx.x;
  if (e >= N_EDGES) return;
  int s = ei[e], d = ei[N_EDGES + e];
  int pos = row_start[d] + atomicAdd(&cur[d], 1);
  eids[pos] = e;
  esrc[pos] = s;
}

// ---------------- node projections ----------------
// Pd[n][256]  f32: [Fdst | Gdst]
// Ppk[n][128] u32: bf16 pairs; word j<64: Fsrc cols (32*(j>>4)+(j&15), +16); j>=64: Gsrc
__global__ __launch_bounds__(256) void k_nodeproj(const float* __restrict__ h,
                                                  const float* __restrict__ Wf_l,
                                                  const float* __restrict__ Ws_l,
                                                  const float* __restrict__ bf_l,
                                                  const float* __restrict__ bs_l,
                                                  float* __restrict__ Pd, u32* __restrict__ Ppk) {
  __shared__ float hrow[HID];
  __shared__ float sF[HID];
  int half = blockIdx.x & 1;
  int tid = threadIdx.x;
  int cc = half * 256 + tid;
  int q = cc >> 7, col = cc & 127;   // half=0 -> q 0(Fdst),1(Fsrc); half=1 -> q 2(Gdst),3(Gsrc)
  const float* W = ((q < 2) ? Wf_l : Ws_l) + (size_t)(q & 1) * HID * HID + col;
  float w[HID];
#pragma unroll
  for (int k = 0; k < HID; k++) w[k] = W[(size_t)k * HID];
  float bias = (q == 0) ? bf_l[col] : ((q == 2) ? bs_l[col] : 0.f);
  for (int node = (blockIdx.x >> 1); node < N_NODES; node += (gridDim.x >> 1)) {
    __syncthreads();
    if (tid < HID) hrow[tid] = h[(size_t)node * HID + tid];
    __syncthreads();
    float acc = bias;
    const float4* h4 = (const float4*)hrow;
#pragma unroll
    for (int k4 = 0; k4 < HID / 4; k4++) {
      float4 hv = h4[k4];
      acc = fmaf(hv.x, w[4 * k4 + 0], acc);
      acc = fmaf(hv.y, w[4 * k4 + 1], acc);
      acc = fmaf(hv.z, w[4 * k4 + 2], acc);
      acc = fmaf(hv.w, w[4 * k4 + 3], acc);
    }
    if ((q & 1) == 0) {
      Pd[(size_t)node * 256 + ((q == 0) ? 0 : 128) + col] = acc;
    } else {
      sF[col] = acc;
    }
    __syncthreads();
    if (tid < 64) {
      int wv = tid >> 4, i = tid & 15;
      float lo = sF[wv * 32 + i], hi = sF[wv * 32 + 16 + i];
      Ppk[(size_t)node * 128 + half * 64 + tid] = f2bf_pack(lo, hi);
    }
  }
}

// ---------------- B-fragment prep (unchanged layout) ----------------
__global__ __launch_bounds__(256) void k_prepB(const float* __restrict__ Wf_l,
                                               const float* __restrict__ Ws_l,
                                               u16* __restrict__ Bhi, u16* __restrict__ Blo) {
  int tid = blockIdx.x * 256 + threadIdx.x;
  if (tid >= 16384) return;
  int i = tid & 7, lane = (tid >> 3) & 63, s = (tid >> 9) & 1, nt = tid >> 10;
  int k = s * 32 + ((lane >> 4) << 3) + i;
  int col = ((nt & 7) << 4) + (lane & 15);
  const float* W = ((nt < 8) ? Wf_l : Ws_l) + 256 * HID;
  float wv = W[k * HID + col];
  u32 u = __float_as_uint(wv);
  u16 hb = (u16)((u + 0x7fff + ((u >> 16) & 1)) >> 16);
  float hf = __uint_as_float((u32)hb << 16);
  float lo = wv - hf;
  u32 ul = __float_as_uint(lo);
  u16 lb = (u16)((ul + 0x7fff + ((ul >> 16) & 1)) >> 16);
  Bhi[tid] = hb;
  Blo[tid] = lb;
}

// ---------------- fused edge MFMA + message + mean-aggregate + residual ----------------
// block = 4 waves on one node; LDS-staged A-frags (double-buffered, XOR-swizzled),
// reg-prefetch pipeline; Psrc gathered as packed bf16 pairs; writes hconv = aggr*inv + h.
__global__ __launch_bounds__(256) void k_edge_mfma(
    const float* __restrict__ Pd, const u32* __restrict__ Ppk,
    const float* __restrict__ h, const float* __restrict__ eattr,
    const int* __restrict__ row_start, const float* __restrict__ inv,
    const int* __restrict__ eids, const int* __restrict__ esrc,
    const u16* __restrict__ Bhi, const u16* __restrict__ Blo,
    float* __restrict__ hconv) {
  __shared__ u16 Alds[2][1024];  // [buf][16 rows][64 k] bf16, swizzled
  const int tid = threadIdx.x;
  const int lane = tid & 63, w = tid >> 6;
  const int l15 = lane & 15, lg = lane >> 4;
  const int cb = w * 32;

  const short8* BH = (const short8*)Bhi;
  const short8* BL = (const short8*)Blo;
  short8 bh[4][2], bl[4][2];
  const int nts[4] = {2 * w, 2 * w + 1, 8 + 2 * w, 9 + 2 * w};
#pragma unroll
  for (int t = 0; t < 4; t++) {
#pragma unroll
    for (int s = 0; s < 2; s++) {
      bh[t][s] = BH[(nts[t] * 2 + s) * 64 + lane];
      bl[t][s] = BL[(nts[t] * 2 + s) * 64 + lane];
    }
  }

  // staging geometry: thread -> (row, 4-elem group)
  const int srow = tid & 15, se4 = tid >> 4;
  const u32 sbyte = (u32)(srow * 128 + ((se4 * 8) ^ ((srow & 7) << 4)));
  // read geometry: lane -> (row=l15, 16B chunk), swizzled
  const u32 rbyte0 = (u32)(l15 * 128 + ((lg * 16) ^ ((l15 & 7) << 4)));
  const u32 rbyte1 = (u32)(l15 * 128 + (((4 + lg) * 16) ^ ((l15 & 7) << 4)));
  const int po1 = w * 16 + l15;       // Ppk word offsets (per lane, const)
  const int po2 = 64 + po1;

  for (int node = blockIdx.x; node < N_NODES; node += gridDim.x) {
    int rs = row_start[node], re = row_start[node + 1];
    int deg = re - rs;
    if (deg == 0) {
      if (lane < 32) {
        size_t idx = (size_t)node * HID + cb + lane;
        hconv[idx] = h[idx];
      }
      continue;
    }
    float fd0 = Pd[(size_t)node * 256 + cb + l15];
    float fd1 = Pd[(size_t)node * 256 + cb + 16 + l15];
    float gd0 = Pd[(size_t)node * 256 + 128 + cb + l15];
    float gd1 = Pd[(size_t)node * 256 + 128 + cb + 16 + l15];
    int ntile = (deg + 15) >> 4;

    // prologue: stage tile 0
    int pe = eids[min(rs + srow, re - 1)];
    float4 av = *(const float4*)(eattr + (size_t)pe * EDIM + se4 * 4);
    __syncthreads();  // prev node's reads done
    *(uint2*)((char*)&Alds[0][0] + sbyte) =
        make_uint2(f2bf_pack(av.x, av.y), f2bf_pack(av.z, av.w));
    __syncthreads();  // buf0 ready

    float acc0 = 0.f, acc1 = 0.f;
    for (int mt = 0; mt < ntile; mt++) {
      bool more = (mt + 1 < ntile);
      if (more) {  // prefetch next tile into regs (hides HBM latency under compute)
        int pe2 = eids[min(rs + (mt + 1) * 16 + srow, re - 1)];
        av = *(const float4*)(eattr + (size_t)pe2 * EDIM + se4 * 4);
      }
      int pos = min(rs + mt * 16 + l15, re - 1);
      int srcl = esrc[pos];
      const char* ab = (const char*)&Alds[mt & 1][0];
      short8 af0 = *(const short8*)(ab + rbyte0);
      short8 af1 = *(const short8*)(ab + rbyte1);
      f32x4 d0 = {fd0, fd0, fd0, fd0};
      f32x4 d1 = {fd1, fd1, fd1, fd1};
      f32x4 d2 = {gd0, gd0, gd0, gd0};
      f32x4 d3 = {gd1, gd1, gd1, gd1};
      d0 = MFMA16(af0, bh[0][0], d0); d0 = MFMA16(af1, bh[0][1], d0);
      d0 = MFMA16(af0, bl[0][0], d0); d0 = MFMA16(af1, bl[0][1], d0);
      d1 = MFMA16(af0, bh[1][0], d1); d1 = MFMA16(af1, bh[1][1], d1);
      d1 = MFMA16(af0, bl[1][0], d1); d1 = MFMA16(af1, bl[1][1], d1);
      d2 = MFMA16(af0, bh[2][0], d2); d2 = MFMA16(af1, bh[2][1], d2);
      d2 = MFMA16(af0, bl[2][0], d2); d2 = MFMA16(af1, bl[2][1], d2);
      d3 = MFMA16(af0, bh[3][0], d3); d3 = MFMA16(af1, bh[3][1], d3);
      d3 = MFMA16(af0, bl[3][0], d3); d3 = MFMA16(af1, bl[3][1], d3);
      int s0 = __shfl(srcl, (lg << 2) + 0);
      int s1 = __shfl(srcl, (lg << 2) + 1);
      int s2 = __shfl(srcl, (lg << 2) + 2);
      int s3 = __shfl(srcl, (lg << 2) + 3);
      const int srcr[4] = {s0, s1, s2, s3};
      bool fullt = ((mt + 1) * 16 <= deg);
#pragma unroll
      for (int r = 0; r < 4; r++) {
        const u32* Pp = Ppk + ((size_t)srcr[r] << 7);
        u32 fp = Pp[po1];
        u32 gp = Pp[po2];
        float f0 = d0[r] + __uint_as_float(fp << 16);
        float f1 = d1[r] + __uint_as_float(fp & 0xffff0000u);
        float g0 = d2[r] + __uint_as_float(gp << 16);
        float g1 = d3[r] + __uint_as_float(gp & 0xffff0000u);
        float m0 = fsig(f0) * fsp(g0);
        float m1 = fsig(f1) * fsp(g1);
        if (!fullt) {
          int row = mt * 16 + (lg << 2) + r;
          if (row >= deg) { m0 = 0.f; m1 = 0.f; }
        }
        acc0 += m0;
        acc1 += m1;
      }
      if (more) {
        __syncthreads();  // all waves done reading buf[(mt+1)&1] (2 tiles ago)
        *(uint2*)((char*)&Alds[(mt + 1) & 1][0] + sbyte) =
            make_uint2(f2bf_pack(av.x, av.y), f2bf_pack(av.z, av.w));
        __syncthreads();  // next buf ready
      }
    }
    acc0 += __shfl_xor(acc0, 16); acc0 += __shfl_xor(acc0, 32);
    acc1 += __shfl_xor(acc1, 16); acc1 += __shfl_xor(acc1, 32);
    float iv = inv[node];
    if (lane < 16) {
      size_t idx = (size_t)node * HID + cb + lane;
      hconv[idx] = acc0 * iv + h[idx];
    } else if (lane < 32) {
      size_t idx = (size_t)node * HID + cb + 16 + l15;
      hconv[idx] = acc1 * iv + h[idx];
    }
  }
}

// ---------------- BN stats (read-only over hconv) ----------------
__global__ __launch_bounds__(256) void k_bn1(const float* __restrict__ hconv,
                                             float* __restrict__ stats) {
  __shared__ float sb[512];
  int c = threadIdx.x & 127;
  int rstream = blockIdx.x * (blockDim.x >> 7) + (threadIdx.x >> 7);
  int nstream = gridDim.x * (blockDim.x >> 7);
  float s1 = 0.f, s2 = 0.f;
  for (int n = rstream; n < N_NODES; n += nstream) {
    float v = hconv[(size_t)n * HID + c];
    s1 += v;
    s2 += v * v;
  }
  sb[threadIdx.x] = s1;
  sb[256 + threadIdx.x] = s2;
  __syncthreads();
  if (threadIdx.x < 128) {
    atomicAdd(&stats[c], sb[threadIdx.x] + sb[threadIdx.x + 128]);
    atomicAdd(&stats[128 + c], sb[256 + threadIdx.x] + sb[256 + threadIdx.x + 128]);
  }
}

__global__ void k_bn2(const float* __restrict__ stats, const float* __restrict__ gamma,
                      const float* __restrict__ beta, float* __restrict__ ss) {
  int c = threadIdx.x;
  if (c < 128) {
    float mu = stats[c] * (1.f / N_NODES);
    float var = stats[128 + c] * (1.f / N_NODES) - mu * mu;
    float sc = gamma[c] * rsqrtf(var + 1e-5f);
    ss[c] = sc;
    ss[128 + c] = beta[c] - mu * sc;
  }
}

__global__ __launch_bounds__(256) void k_bn3(const float* __restrict__ hconv, float* __restrict__ h,
                                             const float* __restrict__ ss) {
  int i = blockIdx.x * blockDim.x + threadIdx.x;
  if (i >= N_NODES * HID) return;
  int c = i & 127;
  float v = hconv[i] * ss[c] + ss[128 + c];
  h[i] = fmaxf(v, 0.f) + h[i];
}

// ---------------- pooling ----------------
__global__ __launch_bounds__(128) void k_pool(const float* __restrict__ h, const int* __restrict__ batch,
                                              float* __restrict__ pooled) {
  int g = blockIdx.x;
  int c = threadIdx.x;
  int lo = 0, hi = N_NODES;
  while (lo < hi) { int m = (lo + hi) >> 1; if (batch[m] < g) lo = m + 1; else hi = m; }
  int s = lo;
  lo = 0; hi = N_NODES;
  while (lo < hi) { int m = (lo + hi) >> 1; if (batch[m] < g + 1) lo = m + 1; else hi = m; }
  int e = lo;
  float acc = 0.f;
  for (int n = s; n < e; n++) acc += h[(size_t)n * HID + c];
  pooled[(size_t)g * HID + c] = acc / (float)max(e - s, 1);
}

// ---------------- head ----------------
__global__ __launch_bounds__(64) void k_head(const float* __restrict__ pooled, const float* __restrict__ W1,
                                             const float* __restrict__ b1, const float* __restrict__ W2,
                                             const float* __restrict__ b2, float* __restrict__ out) {
  int g = blockIdx.x;
  int j = threadIdx.x;
  float acc = b1[j];
#pragma unroll 16
  for (int k = 0; k < 128; k++) acc = fmaf(pooled[(size_t)g * HID + k], W1[k * 64 + j], acc);
  float z = fmaxf(acc, 0.f) + __logf(1.f + __expf(-fabsf(acc)));
  float v = z * W2[j];
  for (int o = 32; o > 0; o >>= 1) v += __shfl_down(v, o);
  if (j == 0) out[g] = v + b2[0];
}

extern "C" void kernel_launch(void* const* d_in, const int* in_sizes, int n_in,
                              void* d_out, int out_size, void* d_ws, size_t ws_size,
                              hipStream_t stream) {
  const float* x     = (const float*)d_in[0];
  const int*   ei    = (const int*)d_in[1];
  const float* eattr = (const float*)d_in[2];
  const int*   batch = (const int*)d_in[3];
  const float* Wemb  = (const float*)d_in[4];
  const float* bemb  = (const float*)d_in[5];
  const float* Wf    = (const float*)d_in[6];
  const float* bf    = (const float*)d_in[7];
  const float* Ws    = (const float*)d_in[8];
  const float* bs    = (const float*)d_in[9];
  const float* gamma = (const float*)d_in[10];
  const float* beta  = (const float*)d_in[11];
  const float* W1    = (const float*)d_in[12];
  const float* b1    = (const float*)d_in[13];
  const float* W2    = (const float*)d_in[14];
  const float* b2    = (const float*)d_in[15];
  float* out = (float*)d_out;

  char* ws = (char*)d_ws;
  size_t off = 0;
  auto alloc = [&](size_t bytes) -> char* {
    char* p = ws + off;
    off += (bytes + 255) & ~(size_t)255;
    return p;
  };
  float* h         = (float*)alloc((size_t)N_NODES * HID * 4);
  float* Pd        = (float*)alloc((size_t)N_NODES * 256 * 4);
  u32*   Ppk       = (u32*)alloc((size_t)N_NODES * 128 * 4);
  float* hconv     = (float*)alloc((size_t)N_NODES * HID * 4);
  int*   row_start = (int*)alloc((size_t)(N_NODES + 1) * 4);
  float* inv       = (float*)alloc((size_t)N_NODES * 4);
  int*   eids      = (int*)alloc((size_t)N_EDGES * 4);
  int*   esrc      = (int*)alloc((size_t)N_EDGES * 4);
  u16*   Bhi       = (u16*)alloc((size_t)16384 * 2);
  u16*   Blo       = (u16*)alloc((size_t)16384 * 2);
  char*  zbase     = ws + off;   // ---- zeroed region start ----
  int*   cnt       = (int*)alloc((size_t)N_NODES * 4);
  int*   cur       = (int*)alloc((size_t)N_NODES * 4);
  float* stats     = (float*)alloc((size_t)NCONV * 256 * 4);
  size_t zbytes    = (size_t)((ws + off) - zbase);
  float* ss        = (float*)alloc(256 * 4);
  int*   bsum      = (int*)alloc(256 * 4);
  float* pooled    = (float*)alloc((size_t)NGRAPH * HID * 4);
  (void)ws_size; (void)in_sizes; (void)n_in; (void)out_size;

  hipMemsetAsync(zbase, 0, zbytes, stream);

  k_embed<<<(N_NODES * HID + 255) / 256, 256, 0, stream>>>(x, Wemb, bemb, h);

  k_count<<<(N_EDGES + 255) / 256, 256, 0, stream>>>(ei, cnt);
  int nb = (N_NODES + 255) / 256;  // 196
  k_scan1<<<nb, 256, 0, stream>>>(cnt, bsum);
  k_scan2<<<1, 256, 0, stream>>>(bsum, nb);
  k_scan3<<<nb, 256, 0, stream>>>(cnt, bsum, row_start, inv);
  k_fill<<<(N_EDGES + 255) / 256, 256, 0, stream>>>(ei, row_start, cur, eids, esrc);

  for (int l = 0; l < NCONV; l++) {
    const float* Wf_l = Wf + (size_t)l * 320 * HID;
    const float* Ws_l = Ws + (size_t)l * 320 * HID;
    k_nodeproj<<<2048, 256, 0, stream>>>(h, Wf_l, Ws_l, bf + l * HID, bs + l * HID, Pd, Ppk);
    k_prepB<<<64, 256, 0, stream>>>(Wf_l, Ws_l, Bhi, Blo);
    k_edge_mfma<<<2048, 256, 0, stream>>>(Pd, Ppk, h, eattr, row_start, inv, eids, esrc,
                                          Bhi, Blo, hconv);
    k_bn1<<<128, 256, 0, stream>>>(hconv, stats + l * 256);
    k_bn2<<<1, 128, 0, stream>>>(stats + l * 256, gamma + l * HID, beta + l * HID, ss);
    k_bn3<<<(N_NODES * HID + 255) / 256, 256, 0, stream>>>(hconv, h, ss);
  }

  k_pool<<<NGRAPH, HID, 0, stream>>>(h, batch, pooled);
  k_head<<<NGRAPH, 64, 0, stream>>>(pooled, W1, b1, W2, b2, out);
}

// Round 5
// 3029.373 us; speedup vs baseline: 3.9103x; 1.2013x over previous
//
#include <hip/hip_runtime.h>
#include <math.h>

#define N_NODES 50000
#define N_EDGES 1600000
#define NGRAPH  512
#define HID     128
#define EDIM    64
#define NCONV   4

typedef __attribute__((ext_vector_type(8))) short short8;
typedef __attribute__((ext_vector_type(4))) float f32x4;
typedef unsigned int  u32;
typedef unsigned short u16;

#define MFMA16(a, b, c) __builtin_amdgcn_mfma_f32_16x16x32_bf16(a, b, c, 0, 0, 0)

__device__ __forceinline__ float fsig(float x) {
  return __fdividef(1.f, 1.f + __expf(-x));
}
__device__ __forceinline__ float fsp(float x) {
  return fmaxf(x, 0.f) + __logf(1.f + __expf(-fabsf(x)));
}
__device__ __forceinline__ u32 f2bf_pack(float lo, float hi) {
  u32 a = __float_as_uint(lo), b = __float_as_uint(hi);
  u32 ra = (a + 0x7fff + ((a >> 16) & 1)) >> 16;
  u32 rb = (b + 0x7fff + ((b >> 16) & 1)) & 0xffff0000u;
  return ra | rb;
}
// pack 8 consecutive f32 (two float4) into 8 bf16 (RNE)
__device__ __forceinline__ short8 cvt8(float4 a, float4 b) {
  union { short8 s; u32 u[4]; } r;
  r.u[0] = f2bf_pack(a.x, a.y);
  r.u[1] = f2bf_pack(a.z, a.w);
  r.u[2] = f2bf_pack(b.x, b.y);
  r.u[3] = f2bf_pack(b.z, b.w);
  return r.s;
}

// ---------------- embed ----------------
__global__ __launch_bounds__(256) void k_embed(const float* __restrict__ x,
                                               const float* __restrict__ Wemb,
                                               const float* __restrict__ bemb,
                                               float* __restrict__ h) {
  int i = blockIdx.x * blockDim.x + threadIdx.x;
  if (i >= N_NODES * HID) return;
  int n = i >> 7, c = i & 127;
  const float* xr = x + (size_t)n * 9;
  float acc = bemb[c];
#pragma unroll
  for (int k = 0; k < 9; k++) acc = fmaf(xr[k], Wemb[k * HID + c], acc);
  h[i] = acc;
}

// ---------------- CSR build ----------------
__global__ __launch_bounds__(256) void k_count(const int* __restrict__ ei, int* __restrict__ cnt) {
  int e = blockIdx.x * blockDim.x + threadIdx.x;
  if (e >= N_EDGES) return;
  atomicAdd(&cnt[ei[N_EDGES + e]], 1);
}

__global__ __launch_bounds__(256) void k_scan1(const int* __restrict__ cnt, int* __restrict__ bsum) {
  __shared__ int s[256];
  int i = blockIdx.x * 256 + threadIdx.x;
  s[threadIdx.x] = (i < N_NODES) ? cnt[i] : 0;
  __syncthreads();
  for (int o = 128; o > 0; o >>= 1) {
    if (threadIdx.x < o) s[threadIdx.x] += s[threadIdx.x + o];
    __syncthreads();
  }
  if (threadIdx.x == 0) bsum[blockIdx.x] = s[0];
}

// parallel exclusive scan of nb (<=256) block sums, one 256-thread block
__global__ __launch_bounds__(256) void k_scan2(int* __restrict__ bsum, int nb) {
  __shared__ int s[256];
  int tid = threadIdx.x;
  s[tid] = (tid < nb) ? bsum[tid] : 0;
  __syncthreads();
  for (int o = 1; o < 256; o <<= 1) {
    int t = (tid >= o) ? s[tid - o] : 0;
    __syncthreads();
    s[tid] += t;
    __syncthreads();
  }
  if (tid < nb) bsum[tid] = (tid == 0) ? 0 : s[tid - 1];
}

__global__ __launch_bounds__(256) void k_scan3(const int* __restrict__ cnt, const int* __restrict__ bsum,
                                               int* __restrict__ row_start, float* __restrict__ inv) {
  __shared__ int s[256];
  int i = blockIdx.x * 256 + threadIdx.x;
  int v = (i < N_NODES) ? cnt[i] : 0;
  s[threadIdx.x] = v;
  __syncthreads();
  for (int o = 1; o < 256; o <<= 1) {
    int t = (threadIdx.x >= o) ? s[threadIdx.x - o] : 0;
    __syncthreads();
    s[threadIdx.x] += t;
    __syncthreads();
  }
  if (i < N_NODES) {
    row_start[i + 1] = s[threadIdx.x] + bsum[blockIdx.x];
    inv[i] = 1.0f / (float)max(v, 1);
    if (i == 0) row_start[0] = 0;
  }
}

__global__ __launch_bounds__(256) void k_fill(const int* __restrict__ ei, const int* __restrict__ row_start,
                                              int* __restrict__ cur, int* __restrict__ eids,
                                              int* __restrict__ esrc) {
  int e = blockIdx.x * blockDim.x + threadIdx.x;
  if (e < 64) {  // zero-pad tails so the edge kernel needs no clamps
    eids[N_EDGES + e] = 0;
    esrc[N_EDGES + e] = 0;
  }
  if (e >= N_EDGES) return;
  int s = ei[e], d = ei[N_EDGES + e];
  int pos = row_start[d] + atomicAdd(&cur[d], 1);
  eids[pos] = e;
  esrc[pos] = s;
}

// ---------------- node projections ----------------
// Pd[n][256]  f32: [Fdst | Gdst]
// Ppk[n][128] u32: bf16 pairs; word j<64: Fsrc cols (32*(j>>4)+(j&15), +16); j>=64: Gsrc
__global__ __launch_bounds__(256) void k_nodeproj(const float* __restrict__ h,
                                                  const float* __restrict__ Wf_l,
                                                  const float* __restrict__ Ws_l,
                                                  const float* __restrict__ bf_l,
                                                  const float* __restrict__ bs_l,
                                                  float* __restrict__ Pd, u32* __restrict__ Ppk) {
  __shared__ float hrow[HID];
  __shared__ float sF[HID];
  int half = blockIdx.x & 1;
  int tid = threadIdx.x;
  int cc = half * 256 + tid;
  int q = cc >> 7, col = cc & 127;   // half=0 -> q 0(Fdst),1(Fsrc); half=1 -> q 2(Gdst),3(Gsrc)
  const float* W = ((q < 2) ? Wf_l : Ws_l) + (size_t)(q & 1) * HID * HID + col;
  float w[HID];
#pragma unroll
  for (int k = 0; k < HID; k++) w[k] = W[(size_t)k * HID];
  float bias = (q == 0) ? bf_l[col] : ((q == 2) ? bs_l[col] : 0.f);
  for (int node = (blockIdx.x >> 1); node < N_NODES; node += (gridDim.x >> 1)) {
    __syncthreads();
    if (tid < HID) hrow[tid] = h[(size_t)node * HID + tid];
    __syncthreads();
    float acc = bias;
    const float4* h4 = (const float4*)hrow;
#pragma unroll
    for (int k4 = 0; k4 < HID / 4; k4++) {
      float4 hv = h4[k4];
      acc = fmaf(hv.x, w[4 * k4 + 0], acc);
      acc = fmaf(hv.y, w[4 * k4 + 1], acc);
      acc = fmaf(hv.z, w[4 * k4 + 2], acc);
      acc = fmaf(hv.w, w[4 * k4 + 3], acc);
    }
    if ((q & 1) == 0) {
      Pd[(size_t)node * 256 + ((q == 0) ? 0 : 128) + col] = acc;
    } else {
      sF[col] = acc;
    }
    __syncthreads();
    if (tid < 64) {
      int wv = tid >> 4, i = tid & 15;
      float lo = sF[wv * 32 + i], hi = sF[wv * 32 + 16 + i];
      Ppk[(size_t)node * 128 + half * 64 + tid] = f2bf_pack(lo, hi);
    }
  }
}

// ---------------- B-fragment prep: W_edge [64,128] -> MFMA frag order, single bf16 ----------------
// Bfrag[nt 0..15][kstep 0..1][lane 0..63][i 0..7]; nt<8 = f (Wf), nt>=8 = g (Ws)
// element = W[k = s*32 + (lane>>4)*8 + i][col = (nt&7)*16 + (lane&15)]
__global__ __launch_bounds__(256) void k_prepB(const float* __restrict__ Wf_l,
                                               const float* __restrict__ Ws_l,
                                               u16* __restrict__ Bhi) {
  int tid = blockIdx.x * 256 + threadIdx.x;
  if (tid >= 16384) return;
  int i = tid & 7, lane = (tid >> 3) & 63, s = (tid >> 9) & 1, nt = tid >> 10;
  int k = s * 32 + ((lane >> 4) << 3) + i;
  int col = ((nt & 7) << 4) + (lane & 15);
  const float* W = ((nt < 8) ? Wf_l : Ws_l) + 256 * HID;
  float wv = W[k * HID + col];
  u32 u = __float_as_uint(wv);
  Bhi[tid] = (u16)((u + 0x7fff + ((u >> 16) & 1)) >> 16);
}

// ---------------- fused edge MFMA + message + mean-aggregate + residual ----------------
// block = 4 independent-ish waves on one node; no LDS, no barriers.
// wave w owns cols [32w,32w+32) of f AND g; M-tile = 16 edges, K = 64, single bf16 W.
__global__ __launch_bounds__(256, 4) void k_edge_mfma(
    const float* __restrict__ Pd, const u32* __restrict__ Ppk,
    const float* __restrict__ h, const float* __restrict__ eattr,
    const int* __restrict__ row_start, const float* __restrict__ inv,
    const int* __restrict__ eids, const int* __restrict__ esrc,
    const u16* __restrict__ Bhi, float* __restrict__ hconv) {
  const int lane = threadIdx.x & 63;
  const int w = threadIdx.x >> 6;
  const int l15 = lane & 15, lg = lane >> 4;
  const int cb = w * 32;

  const short8* BH = (const short8*)Bhi;
  short8 bh[4][2];
  const int nts[4] = {2 * w, 2 * w + 1, 8 + 2 * w, 9 + 2 * w};
#pragma unroll
  for (int t = 0; t < 4; t++) {
#pragma unroll
    for (int s = 0; s < 2; s++) bh[t][s] = BH[(nts[t] * 2 + s) * 64 + lane];
  }
  const int po1 = w * 16 + l15;         // Ppk word offset for col pair (cb+l15, +16)
  const u32 bo1 = (u32)po1 << 2;        // byte offsets within a node's 512B Ppk row
  const u32 bo2 = bo1 + 256;

  for (int node = blockIdx.x; node < N_NODES; node += gridDim.x) {
    int rs = row_start[node], re = row_start[node + 1];
    int deg = re - rs;
    if (deg == 0) {
      if (lane < 32) {
        size_t idx = (size_t)node * HID + cb + lane;
        hconv[idx] = h[idx];
      }
      continue;
    }
    const float* Pn = Pd + (size_t)node * 256;
    float fd0 = Pn[cb + l15];
    float fd1 = Pn[cb + 16 + l15];
    float gd0 = Pn[128 + cb + l15];
    float gd1 = Pn[128 + cb + 16 + l15];
    float acc0 = 0.f, acc1 = 0.f;
    int ntile = (deg + 15) >> 4;
    for (int mt = 0; mt < ntile; mt++) {
      int base = rs + mt * 16;
      int eid = eids[base + l15];                 // padded: no clamp
      const float* ar = eattr + (size_t)eid * EDIM + (lg << 3);
      float4 a0 = *(const float4*)(ar);
      float4 a1 = *(const float4*)(ar + 4);
      float4 a2 = *(const float4*)(ar + 32);
      float4 a3 = *(const float4*)(ar + 36);
      short8 af0 = cvt8(a0, a1);
      short8 af1 = cvt8(a2, a3);
      int srcr[4];
#pragma unroll
      for (int r = 0; r < 4; r++) srcr[r] = esrc[base + (lg << 2) + r];  // broadcast loads
      f32x4 d0 = {fd0, fd0, fd0, fd0};
      f32x4 d1 = {fd1, fd1, fd1, fd1};
      f32x4 d2 = {gd0, gd0, gd0, gd0};
      f32x4 d3 = {gd1, gd1, gd1, gd1};
      d0 = MFMA16(af0, bh[0][0], d0); d0 = MFMA16(af1, bh[0][1], d0);
      d1 = MFMA16(af0, bh[1][0], d1); d1 = MFMA16(af1, bh[1][1], d1);
      d2 = MFMA16(af0, bh[2][0], d2); d2 = MFMA16(af1, bh[2][1], d2);
      d3 = MFMA16(af0, bh[3][0], d3); d3 = MFMA16(af1, bh[3][1], d3);
      bool fullt = ((mt + 1) * 16 <= deg);
#pragma unroll
      for (int r = 0; r < 4; r++) {
        const char* Pp = (const char*)Ppk + (((u32)srcr[r]) << 9);
        u32 fp = *(const u32*)(Pp + bo1);
        u32 gp = *(const u32*)(Pp + bo2);
        float f0 = d0[r] + __uint_as_float(fp << 16);
        float f1 = d1[r] + __uint_as_float(fp & 0xffff0000u);
        float g0 = d2[r] + __uint_as_float(gp << 16);
        float g1 = d3[r] + __uint_as_float(gp & 0xffff0000u);
        float m0 = fsig(f0) * fsp(g0);
        float m1 = fsig(f1) * fsp(g1);
        if (!fullt) {
          int row = mt * 16 + (lg << 2) + r;
          if (row >= deg) { m0 = 0.f; m1 = 0.f; }
        }
        acc0 += m0;
        acc1 += m1;
      }
    }
    acc0 += __shfl_xor(acc0, 16); acc0 += __shfl_xor(acc0, 32);
    acc1 += __shfl_xor(acc1, 16); acc1 += __shfl_xor(acc1, 32);
    float iv = inv[node];
    if (lane < 16) {
      size_t idx = (size_t)node * HID + cb + lane;
      hconv[idx] = acc0 * iv + h[idx];
    } else if (lane < 32) {
      size_t idx = (size_t)node * HID + cb + 16 + l15;
      hconv[idx] = acc1 * iv + h[idx];
    }
  }
}

// ---------------- BN stats (read-only over hconv) ----------------
__global__ __launch_bounds__(256) void k_bn1(const float* __restrict__ hconv,
                                             float* __restrict__ stats) {
  __shared__ float sb[512];
  int c = threadIdx.x & 127;
  int rstream = blockIdx.x * (blockDim.x >> 7) + (threadIdx.x >> 7);
  int nstream = gridDim.x * (blockDim.x >> 7);
  float s1 = 0.f, s2 = 0.f;
  for (int n = rstream; n < N_NODES; n += nstream) {
    float v = hconv[(size_t)n * HID + c];
    s1 += v;
    s2 += v * v;
  }
  sb[threadIdx.x] = s1;
  sb[256 + threadIdx.x] = s2;
  __syncthreads();
  if (threadIdx.x < 128) {
    atomicAdd(&stats[c], sb[threadIdx.x] + sb[threadIdx.x + 128]);
    atomicAdd(&stats[128 + c], sb[256 + threadIdx.x] + sb[256 + threadIdx.x + 128]);
  }
}

__global__ void k_bn2(const float* __restrict__ stats, const float* __restrict__ gamma,
                      const float* __restrict__ beta, float* __restrict__ ss) {
  int c = threadIdx.x;
  if (c < 128) {
    float mu = stats[c] * (1.f / N_NODES);
    float var = stats[128 + c] * (1.f / N_NODES) - mu * mu;
    float sc = gamma[c] * rsqrtf(var + 1e-5f);
    ss[c] = sc;
    ss[128 + c] = beta[c] - mu * sc;
  }
}

__global__ __launch_bounds__(256) void k_bn3(const float* __restrict__ hconv, float* __restrict__ h,
                                             const float* __restrict__ ss) {
  int i = blockIdx.x * blockDim.x + threadIdx.x;
  if (i >= N_NODES * HID) return;
  int c = i & 127;
  float v = hconv[i] * ss[c] + ss[128 + c];
  h[i] = fmaxf(v, 0.f) + h[i];
}

// ---------------- pooling ----------------
__global__ __launch_bounds__(128) void k_pool(const float* __restrict__ h, const int* __restrict__ batch,
                                              float* __restrict__ pooled) {
  int g = blockIdx.x;
  int c = threadIdx.x;
  int lo = 0, hi = N_NODES;
  while (lo < hi) { int m = (lo + hi) >> 1; if (batch[m] < g) lo = m + 1; else hi = m; }
  int s = lo;
  lo = 0; hi = N_NODES;
  while (lo < hi) { int m = (lo + hi) >> 1; if (batch[m] < g + 1) lo = m + 1; else hi = m; }
  int e = lo;
  float acc = 0.f;
  for (int n = s; n < e; n++) acc += h[(size_t)n * HID + c];
  pooled[(size_t)g * HID + c] = acc / (float)max(e - s, 1);
}

// ---------------- head ----------------
__global__ __launch_bounds__(64) void k_head(const float* __restrict__ pooled, const float* __restrict__ W1,
                                             const float* __restrict__ b1, const float* __restrict__ W2,
                                             const float* __restrict__ b2, float* __restrict__ out) {
  int g = blockIdx.x;
  int j = threadIdx.x;
  float acc = b1[j];
#pragma unroll 16
  for (int k = 0; k < 128; k++) acc = fmaf(pooled[(size_t)g * HID + k], W1[k * 64 + j], acc);
  float z = fmaxf(acc, 0.f) + __logf(1.f + __expf(-fabsf(acc)));
  float v = z * W2[j];
  for (int o = 32; o > 0; o >>= 1) v += __shfl_down(v, o);
  if (j == 0) out[g] = v + b2[0];
}

extern "C" void kernel_launch(void* const* d_in, const int* in_sizes, int n_in,
                              void* d_out, int out_size, void* d_ws, size_t ws_size,
                              hipStream_t stream) {
  const float* x     = (const float*)d_in[0];
  const int*   ei    = (const int*)d_in[1];
  const float* eattr = (const float*)d_in[2];
  const int*   batch = (const int*)d_in[3];
  const float* Wemb  = (const float*)d_in[4];
  const float* bemb  = (const float*)d_in[5];
  const float* Wf    = (const float*)d_in[6];
  const float* bf    = (const float*)d_in[7];
  const float* Ws    = (const float*)d_in[8];
  const float* bs    = (const float*)d_in[9];
  const float* gamma = (const float*)d_in[10];
  const float* beta  = (const float*)d_in[11];
  const float* W1    = (const float*)d_in[12];
  const float* b1    = (const float*)d_in[13];
  const float* W2    = (const float*)d_in[14];
  const float* b2    = (const float*)d_in[15];
  float* out = (float*)d_out;

  char* ws = (char*)d_ws;
  size_t off = 0;
  auto alloc = [&](size_t bytes) -> char* {
    char* p = ws + off;
    off += (bytes + 255) & ~(size_t)255;
    return p;
  };
  float* h         = (float*)alloc((size_t)N_NODES * HID * 4);
  float* Pd        = (float*)alloc((size_t)N_NODES * 256 * 4);
  u32*   Ppk       = (u32*)alloc((size_t)N_NODES * 128 * 4);
  float* hconv     = (float*)alloc((size_t)N_NODES * HID * 4);
  int*   row_start = (int*)alloc((size_t)(N_NODES + 1) * 4);
  float* inv       = (float*)alloc((size_t)N_NODES * 4);
  int*   eids      = (int*)alloc((size_t)(N_EDGES + 64) * 4);
  int*   esrc      = (int*)alloc((size_t)(N_EDGES + 64) * 4);
  u16*   Bhi       = (u16*)alloc((size_t)16384 * 2);
  char*  zbase     = ws + off;   // ---- zeroed region start ----
  int*   cnt       = (int*)alloc((size_t)N_NODES * 4);
  int*   cur       = (int*)alloc((size_t)N_NODES * 4);
  float* stats     = (float*)alloc((size_t)NCONV * 256 * 4);
  size_t zbytes    = (size_t)((ws + off) - zbase);
  float* ss        = (float*)alloc(256 * 4);
  int*   bsum      = (int*)alloc(256 * 4);
  float* pooled    = (float*)alloc((size_t)NGRAPH * HID * 4);
  (void)ws_size; (void)in_sizes; (void)n_in; (void)out_size;

  hipMemsetAsync(zbase, 0, zbytes, stream);

  k_embed<<<(N_NODES * HID + 255) / 256, 256, 0, stream>>>(x, Wemb, bemb, h);

  k_count<<<(N_EDGES + 255) / 256, 256, 0, stream>>>(ei, cnt);
  int nb = (N_NODES + 255) / 256;  // 196
  k_scan1<<<nb, 256, 0, stream>>>(cnt, bsum);
  k_scan2<<<1, 256, 0, stream>>>(bsum, nb);
  k_scan3<<<nb, 256, 0, stream>>>(cnt, bsum, row_start, inv);
  k_fill<<<(N_EDGES + 255) / 256, 256, 0, stream>>>(ei, row_start, cur, eids, esrc);

  for (int l = 0; l < NCONV; l++) {
    const float* Wf_l = Wf + (size_t)l * 320 * HID;
    const float* Ws_l = Ws + (size_t)l * 320 * HID;
    k_nodeproj<<<2048, 256, 0, stream>>>(h, Wf_l, Ws_l, bf + l * HID, bs + l * HID, Pd, Ppk);
    k_prepB<<<64, 256, 0, stream>>>(Wf_l, Ws_l, Bhi);
    k_edge_mfma<<<4096, 256, 0, stream>>>(Pd, Ppk, h, eattr, row_start, inv, eids, esrc,
                                          Bhi, hconv);
    k_bn1<<<128, 256, 0, stream>>>(hconv, stats + l * 256);
    k_bn2<<<1, 128, 0, stream>>>(stats + l * 256, gamma + l * HID, beta + l * HID, ss);
    k_bn3<<<(N_NODES * HID + 255) / 256, 256, 0, stream>>>(hconv, h, ss);
  }

  k_pool<<<NGRAPH, HID, 0, stream>>>(h, batch, pooled);
  k_head<<<NGRAPH, 64, 0, stream>>>(pooled, W1, b1, W2, b2, out);
}

// Round 6
// 2498.845 us; speedup vs baseline: 4.7404x; 1.2123x over previous
//
#include <hip/hip_runtime.h>
#include <math.h>

#define N_NODES 50000
#define N_EDGES 1600000
#define NGRAPH  512
#define HID     128
#define EDIM    64
#define NCONV   4

typedef __attribute__((ext_vector_type(8))) short short8;
typedef __attribute__((ext_vector_type(4))) float f32x4;
typedef unsigned int  u32;
typedef unsigned short u16;

#define MFMA16(a, b, c) __builtin_amdgcn_mfma_f32_16x16x32_bf16(a, b, c, 0, 0, 0)

__device__ __forceinline__ float fsig(float x) {
  return __fdividef(1.f, 1.f + __expf(-x));
}
__device__ __forceinline__ float fsp(float x) {
  return fmaxf(x, 0.f) + __logf(1.f + __expf(-fabsf(x)));
}
__device__ __forceinline__ u16 f2bf(float x) {
  u32 u = __float_as_uint(x);
  return (u16)((u + 0x7fff + ((u >> 16) & 1)) >> 16);
}
__device__ __forceinline__ u32 f2bf_pack(float lo, float hi) {
  u32 a = __float_as_uint(lo), b = __float_as_uint(hi);
  u32 ra = (a + 0x7fff + ((a >> 16) & 1)) >> 16;
  u32 rb = (b + 0x7fff + ((b >> 16) & 1)) & 0xffff0000u;
  return ra | rb;
}
// pack 8 consecutive f32 (two float4) into 8 bf16 (RNE)
__device__ __forceinline__ short8 cvt8(float4 a, float4 b) {
  union { short8 s; u32 u[4]; } r;
  r.u[0] = f2bf_pack(a.x, a.y);
  r.u[1] = f2bf_pack(a.z, a.w);
  r.u[2] = f2bf_pack(b.x, b.y);
  r.u[3] = f2bf_pack(b.z, b.w);
  return r.s;
}

// ---------------- embed: h = x @ W_emb + b_emb (+ bf16 hi/lo split of h) ----------------
__global__ __launch_bounds__(256) void k_embed(const float* __restrict__ x,
                                               const float* __restrict__ Wemb,
                                               const float* __restrict__ bemb,
                                               float* __restrict__ h,
                                               u16* __restrict__ hb, u16* __restrict__ hlo) {
  int i = blockIdx.x * blockDim.x + threadIdx.x;
  if (i >= N_NODES * HID) return;
  int n = i >> 7, c = i & 127;
  const float* xr = x + (size_t)n * 9;
  float acc = bemb[c];
#pragma unroll
  for (int k = 0; k < 9; k++) acc = fmaf(xr[k], Wemb[k * HID + c], acc);
  h[i] = acc;
  u16 hi16 = f2bf(acc);
  hb[i] = hi16;
  hlo[i] = f2bf(acc - __uint_as_float((u32)hi16 << 16));
}

// ---------------- CSR build ----------------
__global__ __launch_bounds__(256) void k_count(const int* __restrict__ ei, int* __restrict__ cnt) {
  int e = blockIdx.x * blockDim.x + threadIdx.x;
  if (e >= N_EDGES) return;
  atomicAdd(&cnt[ei[N_EDGES + e]], 1);
}

__global__ __launch_bounds__(256) void k_scan1(const int* __restrict__ cnt, int* __restrict__ bsum) {
  __shared__ int s[256];
  int i = blockIdx.x * 256 + threadIdx.x;
  s[threadIdx.x] = (i < N_NODES) ? cnt[i] : 0;
  __syncthreads();
  for (int o = 128; o > 0; o >>= 1) {
    if (threadIdx.x < o) s[threadIdx.x] += s[threadIdx.x + o];
    __syncthreads();
  }
  if (threadIdx.x == 0) bsum[blockIdx.x] = s[0];
}

__global__ __launch_bounds__(256) void k_scan2(int* __restrict__ bsum, int nb) {
  __shared__ int s[256];
  int tid = threadIdx.x;
  s[tid] = (tid < nb) ? bsum[tid] : 0;
  __syncthreads();
  for (int o = 1; o < 256; o <<= 1) {
    int t = (tid >= o) ? s[tid - o] : 0;
    __syncthreads();
    s[tid] += t;
    __syncthreads();
  }
  if (tid < nb) bsum[tid] = (tid == 0) ? 0 : s[tid - 1];
}

__global__ __launch_bounds__(256) void k_scan3(const int* __restrict__ cnt, const int* __restrict__ bsum,
                                               int* __restrict__ row_start, float* __restrict__ inv) {
  __shared__ int s[256];
  int i = blockIdx.x * 256 + threadIdx.x;
  int v = (i < N_NODES) ? cnt[i] : 0;
  s[threadIdx.x] = v;
  __syncthreads();
  for (int o = 1; o < 256; o <<= 1) {
    int t = (threadIdx.x >= o) ? s[threadIdx.x - o] : 0;
    __syncthreads();
    s[threadIdx.x] += t;
    __syncthreads();
  }
  if (i < N_NODES) {
    row_start[i + 1] = s[threadIdx.x] + bsum[blockIdx.x];
    inv[i] = 1.0f / (float)max(v, 1);
    if (i == 0) row_start[0] = 0;
  }
}

__global__ __launch_bounds__(256) void k_fill(const int* __restrict__ ei, const int* __restrict__ row_start,
                                              int* __restrict__ cur, int* __restrict__ eids,
                                              int* __restrict__ esrc) {
  int e = blockIdx.x * blockDim.x + threadIdx.x;
  if (e < 64) {  // zero-pad tails so the edge kernel needs no clamps
    eids[N_EDGES + e] = 0;
    esrc[N_EDGES + e] = 0;
  }
  if (e >= N_EDGES) return;
  int s = ei[e], d = ei[N_EDGES + e];
  int pos = row_start[d] + atomicAdd(&cur[d], 1);
  eids[pos] = e;
  esrc[pos] = s;
}

// ---------------- one-time: gather edge_attr into CSR order as bf16 ----------------
// Ae[pos][64] bf16 (128B rows); pad rows zeroed.
__global__ __launch_bounds__(256) void k_gatherA(const float* __restrict__ eattr,
                                                 const int* __restrict__ eids,
                                                 u16* __restrict__ Ae) {
  int t = blockIdx.x * 256 + threadIdx.x;   // t = pos*8 + chunk
  if (t >= (N_EDGES + 64) * 8) return;
  int pos = t >> 3, chunk = t & 7;
  short8* dst = (short8*)((char*)Ae + ((size_t)pos << 7) + (chunk << 4));
  if (pos >= N_EDGES) {
    union { short8 s; u32 u[4]; } z; z.u[0] = z.u[1] = z.u[2] = z.u[3] = 0;
    *dst = z.s;
    return;
  }
  int eid = eids[pos];
  const float* src = eattr + ((size_t)eid << 6) + (chunk << 3);
  float4 a = *(const float4*)src;
  float4 b = *(const float4*)(src + 4);
  *dst = cvt8(a, b);
}

// ---------------- W node-part frag pack: [128,512] -> MFMA frag order, hi+lo ----------------
// cols 0-127 Fdst(Wf rows 0-127), 128-255 Fsrc(Wf rows 128-255), 256-383 Gdst(Ws), 384-511 Gsrc(Ws)
// idx = (((q*8+nt)*4+s)*64 + lane)*8 + i  with col=q*128+nt*16+(lane&15), k=s*32+(lane>>4)*8+i
__global__ __launch_bounds__(256) void k_prepW(const float* __restrict__ Wf_l,
                                               const float* __restrict__ Ws_l,
                                               u16* __restrict__ Whi, u16* __restrict__ Wlo) {
  int t = blockIdx.x * 256 + threadIdx.x;
  if (t >= 65536) return;
  int c = t >> 7, k = t & 127;
  int q = c >> 7, col = c & 127;
  const float* W = (q < 2) ? Wf_l : Ws_l;
  int row = (q & 1) ? (128 + k) : k;
  float wv = W[row * HID + col];
  u16 hb16 = f2bf(wv);
  float lo = wv - __uint_as_float((u32)hb16 << 16);
  int nt = (c >> 4) & 7, l15 = c & 15;
  int s = k >> 5, lg = (k >> 3) & 3, i = k & 7;
  int idx = (((q * 8 + nt) * 4 + s) * 64 + (lg * 16 + l15)) * 8 + i;
  Whi[idx] = hb16;
  Wlo[idx] = f2bf(lo);
}

// ---------------- W edge-part frag pack (single bf16) ----------------
__global__ __launch_bounds__(256) void k_prepB(const float* __restrict__ Wf_l,
                                               const float* __restrict__ Ws_l,
                                               u16* __restrict__ Bhi) {
  int tid = blockIdx.x * 256 + threadIdx.x;
  if (tid >= 16384) return;
  int i = tid & 7, lane = (tid >> 3) & 63, s = (tid >> 9) & 1, nt = tid >> 10;
  int k = s * 32 + ((lane >> 4) << 3) + i;
  int col = ((nt & 7) << 4) + (lane & 15);
  const float* W = ((nt < 8) ? Wf_l : Ws_l) + 256 * HID;
  Bhi[tid] = f2bf(W[k * HID + col]);
}

// ---------------- node projection GEMM via MFMA: [50K,128] @ [128,512] ----------------
// block = 4 waves, 16 nodes; wave w -> cols [128w,128w+128). 3-pass hi/lo split (~f32 exact).
// Pd[n][256] f32 [Fdst|Gdst] (+bias); Ppk[n][128] u32 interleaved: word 2j=F-pair j, 2j+1=G-pair j
__global__ __launch_bounds__(256) void k_nodeproj_mfma(
    const u16* __restrict__ hb, const u16* __restrict__ hlo,
    const u16* __restrict__ Whi, const u16* __restrict__ Wlo,
    const float* __restrict__ bf_l, const float* __restrict__ bs_l,
    float* __restrict__ Pd, u32* __restrict__ Ppk) {
  const int lane = threadIdx.x & 63, w = threadIdx.x >> 6;
  const int l15 = lane & 15, lg = lane >> 4;
  const int nb = blockIdx.x * 16;
  const short8* WH = (const short8*)Whi;
  const short8* WL = (const short8*)Wlo;
  f32x4 acc[8];
#pragma unroll
  for (int nt = 0; nt < 8; nt++) acc[nt] = (f32x4){0.f, 0.f, 0.f, 0.f};
  const u32 arow = ((u32)(nb + l15)) << 8;
#pragma unroll
  for (int s = 0; s < 4; s++) {
    u32 ao = arow + (s << 6) + (lg << 4);
    short8 ah = *(const short8*)((const char*)hb + ao);
    short8 al = *(const short8*)((const char*)hlo + ao);
#pragma unroll
    for (int nt = 0; nt < 8; nt++) {
      int bi = ((w * 8 + nt) * 4 + s) * 64 + lane;
      short8 bhv = WH[bi];
      short8 blv = WL[bi];
      acc[nt] = MFMA16(ah, bhv, acc[nt]);
      acc[nt] = MFMA16(ah, blv, acc[nt]);
      acc[nt] = MFMA16(al, bhv, acc[nt]);
    }
  }
  if ((w & 1) == 0) {  // w0 -> Fdst, w2 -> Gdst (f32 + bias)
    const float* bias = (w == 0) ? bf_l : bs_l;
    int pdoff = (w == 0) ? 0 : 128;
#pragma unroll
    for (int nt = 0; nt < 8; nt++) {
      int col = nt * 16 + l15;
      float b = bias[col];
#pragma unroll
      for (int r = 0; r < 4; r++) {
        int node = nb + lg * 4 + r;
        Pd[(size_t)node * 256 + pdoff + col] = acc[nt][r] + b;
      }
    }
  } else {             // w1 -> Fsrc (.x words), w3 -> Gsrc (.y words)
    int off = (w == 1) ? 0 : 1;
#pragma unroll
    for (int g = 0; g < 4; g++) {
#pragma unroll
      for (int r = 0; r < 4; r++) {
        int node = nb + lg * 4 + r;
        Ppk[(size_t)node * 128 + 2 * (g * 16 + l15) + off] =
            f2bf_pack(acc[2 * g][r], acc[2 * g + 1][r]);
      }
    }
  }
}

// ---------------- fused edge MFMA + message + mean-aggregate + residual ----------------
// A streamed from pre-gathered bf16 CSR tiles (no cvt, no indirection); Ppk uint2 gathers.
__global__ __launch_bounds__(256, 5) void k_edge_mfma(
    const float* __restrict__ Pd, const u32* __restrict__ Ppk,
    const float* __restrict__ h, const u16* __restrict__ Ae,
    const int* __restrict__ row_start, const float* __restrict__ inv,
    const int* __restrict__ esrc, const u16* __restrict__ Bhi,
    float* __restrict__ hconv) {
  const int lane = threadIdx.x & 63;
  const int w = threadIdx.x >> 6;
  const int l15 = lane & 15, lg = lane >> 4;
  const int cb = w * 32;

  const short8* BH = (const short8*)Bhi;
  short8 bh[4][2];
  const int nts[4] = {2 * w, 2 * w + 1, 8 + 2 * w, 9 + 2 * w};
#pragma unroll
  for (int t = 0; t < 4; t++) {
#pragma unroll
    for (int s = 0; s < 2; s++) bh[t][s] = BH[(nts[t] * 2 + s) * 64 + lane];
  }
  const u32 poff = ((u32)(w * 16 + l15)) << 3;  // uint2 byte offset in 512B Ppk row

  for (int node = blockIdx.x; node < N_NODES; node += gridDim.x) {
    int rs = row_start[node], re = row_start[node + 1];
    int deg = re - rs;
    if (deg == 0) {
      if (lane < 32) {
        size_t idx = (size_t)node * HID + cb + lane;
        hconv[idx] = h[idx];
      }
      continue;
    }
    const float* Pn = Pd + (size_t)node * 256;
    float fd0 = Pn[cb + l15];
    float fd1 = Pn[cb + 16 + l15];
    float gd0 = Pn[128 + cb + l15];
    float gd1 = Pn[128 + cb + 16 + l15];
    float acc0 = 0.f, acc1 = 0.f;
    int ntile = (deg + 15) >> 4;
    for (int mt = 0; mt < ntile; mt++) {
      int base = rs + mt * 16;
      u32 ab = ((u32)(base + l15) << 7) + ((u32)lg << 4);
      short8 af0 = *(const short8*)((const char*)Ae + ab);
      short8 af1 = *(const short8*)((const char*)Ae + ab + 64);
      int srcr[4];
#pragma unroll
      for (int r = 0; r < 4; r++) srcr[r] = esrc[base + (lg << 2) + r];  // broadcast loads
      f32x4 d0 = {fd0, fd0, fd0, fd0};
      f32x4 d1 = {fd1, fd1, fd1, fd1};
      f32x4 d2 = {gd0, gd0, gd0, gd0};
      f32x4 d3 = {gd1, gd1, gd1, gd1};
      d0 = MFMA16(af0, bh[0][0], d0); d0 = MFMA16(af1, bh[0][1], d0);
      d1 = MFMA16(af0, bh[1][0], d1); d1 = MFMA16(af1, bh[1][1], d1);
      d2 = MFMA16(af0, bh[2][0], d2); d2 = MFMA16(af1, bh[2][1], d2);
      d3 = MFMA16(af0, bh[3][0], d3); d3 = MFMA16(af1, bh[3][1], d3);
      bool fullt = ((mt + 1) * 16 <= deg);
#pragma unroll
      for (int r = 0; r < 4; r++) {
        uint2 pg = *(const uint2*)((const char*)Ppk + (((u32)srcr[r]) << 9) + poff);
        float f0 = d0[r] + __uint_as_float(pg.x << 16);
        float f1 = d1[r] + __uint_as_float(pg.x & 0xffff0000u);
        float g0 = d2[r] + __uint_as_float(pg.y << 16);
        float g1 = d3[r] + __uint_as_float(pg.y & 0xffff0000u);
        float m0 = fsig(f0) * fsp(g0);
        float m1 = fsig(f1) * fsp(g1);
        if (!fullt) {
          int row = mt * 16 + (lg << 2) + r;
          if (row >= deg) { m0 = 0.f; m1 = 0.f; }
        }
        acc0 += m0;
        acc1 += m1;
      }
    }
    acc0 += __shfl_xor(acc0, 16); acc0 += __shfl_xor(acc0, 32);
    acc1 += __shfl_xor(acc1, 16); acc1 += __shfl_xor(acc1, 32);
    float iv = inv[node];
    if (lane < 16) {
      size_t idx = (size_t)node * HID + cb + lane;
      hconv[idx] = acc0 * iv + h[idx];
    } else if (lane < 32) {
      size_t idx = (size_t)node * HID + cb + 16 + l15;
      hconv[idx] = acc1 * iv + h[idx];
    }
  }
}

// ---------------- BN stats (read-only over hconv) ----------------
__global__ __launch_bounds__(256) void k_bn1(const float* __restrict__ hconv,
                                             float* __restrict__ stats) {
  __shared__ float sb[512];
  int c = threadIdx.x & 127;
  int rstream = blockIdx.x * (blockDim.x >> 7) + (threadIdx.x >> 7);
  int nstream = gridDim.x * (blockDim.x >> 7);
  float s1 = 0.f, s2 = 0.f;
  for (int n = rstream; n < N_NODES; n += nstream) {
    float v = hconv[(size_t)n * HID + c];
    s1 += v;
    s2 += v * v;
  }
  sb[threadIdx.x] = s1;
  sb[256 + threadIdx.x] = s2;
  __syncthreads();
  if (threadIdx.x < 128) {
    atomicAdd(&stats[c], sb[threadIdx.x] + sb[threadIdx.x + 128]);
    atomicAdd(&stats[128 + c], sb[256 + threadIdx.x] + sb[256 + threadIdx.x + 128]);
  }
}

__global__ void k_bn2(const float* __restrict__ stats, const float* __restrict__ gamma,
                      const float* __restrict__ beta, float* __restrict__ ss) {
  int c = threadIdx.x;
  if (c < 128) {
    float mu = stats[c] * (1.f / N_NODES);
    float var = stats[128 + c] * (1.f / N_NODES) - mu * mu;
    float sc = gamma[c] * rsqrtf(var + 1e-5f);
    ss[c] = sc;
    ss[128 + c] = beta[c] - mu * sc;
  }
}

// bn apply + relu + residual; also emit bf16 hi/lo split of new h
__global__ __launch_bounds__(256) void k_bn3(const float* __restrict__ hconv, float* __restrict__ h,
                                             const float* __restrict__ ss,
                                             u16* __restrict__ hb, u16* __restrict__ hlo) {
  int i = blockIdx.x * blockDim.x + threadIdx.x;
  if (i >= N_NODES * HID) return;
  int c = i & 127;
  float v = hconv[i] * ss[c] + ss[128 + c];
  float hn = fmaxf(v, 0.f) + h[i];
  h[i] = hn;
  u16 hi16 = f2bf(hn);
  hb[i] = hi16;
  hlo[i] = f2bf(hn - __uint_as_float((u32)hi16 << 16));
}

// ---------------- pooling ----------------
__global__ __launch_bounds__(128) void k_pool(const float* __restrict__ h, const int* __restrict__ batch,
                                              float* __restrict__ pooled) {
  int g = blockIdx.x;
  int c = threadIdx.x;
  int lo = 0, hi = N_NODES;
  while (lo < hi) { int m = (lo + hi) >> 1; if (batch[m] < g) lo = m + 1; else hi = m; }
  int s = lo;
  lo = 0; hi = N_NODES;
  while (lo < hi) { int m = (lo + hi) >> 1; if (batch[m] < g + 1) lo = m + 1; else hi = m; }
  int e = lo;
  float acc = 0.f;
  for (int n = s; n < e; n++) acc += h[(size_t)n * HID + c];
  pooled[(size_t)g * HID + c] = acc / (float)max(e - s, 1);
}

// ---------------- head ----------------
__global__ __launch_bounds__(64) void k_head(const float* __restrict__ pooled, const float* __restrict__ W1,
                                             const float* __restrict__ b1, const float* __restrict__ W2,
                                             const float* __restrict__ b2, float* __restrict__ out) {
  int g = blockIdx.x;
  int j = threadIdx.x;
  float acc = b1[j];
#pragma unroll 16
  for (int k = 0; k < 128; k++) acc = fmaf(pooled[(size_t)g * HID + k], W1[k * 64 + j], acc);
  float z = fmaxf(acc, 0.f) + __logf(1.f + __expf(-fabsf(acc)));
  float v = z * W2[j];
  for (int o = 32; o > 0; o >>= 1) v += __shfl_down(v, o);
  if (j == 0) out[g] = v + b2[0];
}

extern "C" void kernel_launch(void* const* d_in, const int* in_sizes, int n_in,
                              void* d_out, int out_size, void* d_ws, size_t ws_size,
                              hipStream_t stream) {
  const float* x     = (const float*)d_in[0];
  const int*   ei    = (const int*)d_in[1];
  const float* eattr = (const float*)d_in[2];
  const int*   batch = (const int*)d_in[3];
  const float* Wemb  = (const float*)d_in[4];
  const float* bemb  = (const float*)d_in[5];
  const float* Wf    = (const float*)d_in[6];
  const float* bf    = (const float*)d_in[7];
  const float* Ws    = (const float*)d_in[8];
  const float* bs    = (const float*)d_in[9];
  const float* gamma = (const float*)d_in[10];
  const float* beta  = (const float*)d_in[11];
  const float* W1    = (const float*)d_in[12];
  const float* b1    = (const float*)d_in[13];
  const float* W2    = (const float*)d_in[14];
  const float* b2    = (const float*)d_in[15];
  float* out = (float*)d_out;

  char* ws = (char*)d_ws;
  size_t off = 0;
  auto alloc = [&](size_t bytes) -> char* {
    char* p = ws + off;
    off += (bytes + 255) & ~(size_t)255;
    return p;
  };
  float* h         = (float*)alloc((size_t)N_NODES * HID * 4);
  u16*   hb        = (u16*)alloc((size_t)N_NODES * HID * 2);
  u16*   hlo       = (u16*)alloc((size_t)N_NODES * HID * 2);
  float* Pd        = (float*)alloc((size_t)N_NODES * 256 * 4);
  u32*   Ppk       = (u32*)alloc((size_t)N_NODES * 128 * 4);
  float* hconv     = (float*)alloc((size_t)N_NODES * HID * 4);
  int*   row_start = (int*)alloc((size_t)(N_NODES + 1) * 4);
  float* inv       = (float*)alloc((size_t)N_NODES * 4);
  int*   eids      = (int*)alloc((size_t)(N_EDGES + 64) * 4);
  int*   esrc      = (int*)alloc((size_t)(N_EDGES + 64) * 4);
  u16*   Ae        = (u16*)alloc((size_t)(N_EDGES + 64) * EDIM * 2);
  u16*   Bhi       = (u16*)alloc((size_t)16384 * 2);
  u16*   Whi       = (u16*)alloc((size_t)65536 * 2);
  u16*   Wlo       = (u16*)alloc((size_t)65536 * 2);
  char*  zbase     = ws + off;   // ---- zeroed region start ----
  int*   cnt       = (int*)alloc((size_t)N_NODES * 4);
  int*   cur       = (int*)alloc((size_t)N_NODES * 4);
  float* stats     = (float*)alloc((size_t)NCONV * 256 * 4);
  size_t zbytes    = (size_t)((ws + off) - zbase);
  float* ss        = (float*)alloc(256 * 4);
  int*   bsum      = (int*)alloc(256 * 4);
  float* pooled    = (float*)alloc((size_t)NGRAPH * HID * 4);
  (void)ws_size; (void)in_sizes; (void)n_in; (void)out_size;

  hipMemsetAsync(zbase, 0, zbytes, stream);

  k_embed<<<(N_NODES * HID + 255) / 256, 256, 0, stream>>>(x, Wemb, bemb, h, hb, hlo);

  k_count<<<(N_EDGES + 255) / 256, 256, 0, stream>>>(ei, cnt);
  int nb = (N_NODES + 255) / 256;  // 196
  k_scan1<<<nb, 256, 0, stream>>>(cnt, bsum);
  k_scan2<<<1, 256, 0, stream>>>(bsum, nb);
  k_scan3<<<nb, 256, 0, stream>>>(cnt, bsum, row_start, inv);
  k_fill<<<(N_EDGES + 255) / 256, 256, 0, stream>>>(ei, row_start, cur, eids, esrc);
  k_gatherA<<<((N_EDGES + 64) * 8 + 255) / 256, 256, 0, stream>>>(eattr, eids, Ae);

  for (int l = 0; l < NCONV; l++) {
    const float* Wf_l = Wf + (size_t)l * 320 * HID;
    const float* Ws_l = Ws + (size_t)l * 320 * HID;
    k_prepW<<<256, 256, 0, stream>>>(Wf_l, Ws_l, Whi, Wlo);
    k_prepB<<<64, 256, 0, stream>>>(Wf_l, Ws_l, Bhi);
    k_nodeproj_mfma<<<N_NODES / 16, 256, 0, stream>>>(hb, hlo, Whi, Wlo,
                                                      bf + l * HID, bs + l * HID, Pd, Ppk);
    k_edge_mfma<<<4096, 256, 0, stream>>>(Pd, Ppk, h, Ae, row_start, inv, esrc, Bhi, hconv);
    k_bn1<<<128, 256, 0, stream>>>(hconv, stats + l * 256);
    k_bn2<<<1, 128, 0, stream>>>(stats + l * 256, gamma + l * HID, beta + l * HID, ss);
    k_bn3<<<(N_NODES * HID + 255) / 256, 256, 0, stream>>>(hconv, h, ss, hb, hlo);
  }

  k_pool<<<NGRAPH, HID, 0, stream>>>(h, batch, pooled);
  k_head<<<NGRAPH, 64, 0, stream>>>(pooled, W1, b1, W2, b2, out);
}